// Round 20
// baseline (745.173 us; speedup 1.0000x reference)
//
#include <hip/hip_runtime.h>

#define N_NODES 100000
#define N_EDGES 1600000
#define N_GRAPHS 64
#define DIM 128
#define BN_EPS 1e-5f
#define EPAD 2000000          // sentinel-filled esrc capacity (needs 1,903,419)

#define NB_SENT 977           // esrc sentinel fill, 8 per thread
#define NB_WPREP 192          // 3*128*128/256
#define NB_HIST 391           // coarse hist: 391 chunks * 4096 edges
#define NBUCK 782             // coarse buckets = id>>7 (100000/128)
#define NG (NBUCK * NB_HIST)  // per-side count-matrix size = 305762
#define NB_SCANG2 2389        // ceil(2*NG/256)
#define BUCK_RESERVE 388      // cnt + 128*3 pad + 4 align slack

#define AT_STRIDE 136  // 128 + 8 pad: 2-way-only LDS bank aliasing

typedef unsigned short ushort_t;
typedef unsigned char uchar_t;
typedef unsigned int uint_t;
typedef __attribute__((ext_vector_type(8))) short bf16x8;
typedef __attribute__((ext_vector_type(4))) float f32x4;

__device__ __forceinline__ float bfl(uint_t u) {
    union { uint_t i; float f; } v; v.i = u << 16; return v.f;
}
__device__ __forceinline__ float bfh(uint_t u) {
    union { uint_t i; float f; } v; v.i = u & 0xffff0000u; return v.f;
}
__device__ __forceinline__ ushort_t f2bf(float f) {
    union { float f; uint_t i; } v; v.f = f;
    uint_t x = v.i;
    return (ushort_t)((x + 0x7fffu + ((x >> 16) & 1u)) >> 16);
}
__device__ __forceinline__ uint_t pack2(float lo, float hi) {
    return ((uint_t)f2bf(hi) << 16) | (uint_t)f2bf(lo);
}

// ---------------- zero scratch ----------------
__global__ void k_zero(int* __restrict__ p, int n) {
    int i = blockIdx.x * blockDim.x + threadIdx.x;
    if (i < n) p[i] = 0;
}

// ---------------- front mega-kernel: {sentinel | wprep | dual coarse-hist} ----------------
__global__ void k_front(const int* __restrict__ src, const int* __restrict__ dst,
                        ushort_t* __restrict__ bufA, int* __restrict__ esrc,
                        const float* __restrict__ w1, const float* __restrict__ w2,
                        const float* __restrict__ w3, ushort_t* __restrict__ wbt,
                        int* __restrict__ GG) {
    __shared__ int hh[NBUCK];
    __shared__ int hh2[NBUCK];
    int b = blockIdx.x;
    int t = threadIdx.x;
    if (b < NB_SENT) {  // esrc sentinel fill + zero bufA sentinel feature row
        int i0 = (b * 256 + t) * 8;
        int4 sv = make_int4(N_NODES, N_NODES, N_NODES, N_NODES);
        if (i0 + 8 <= EPAD) {
            *(int4*)(esrc + i0) = sv;
            *(int4*)(esrc + i0 + 4) = sv;
        } else {
            for (int i = i0; i < EPAD; ++i) esrc[i] = N_NODES;
        }
        if (b == 0 && t < 64)
            ((uint_t*)(bufA + (size_t)N_NODES * DIM))[t] = 0u;
        return;
    }
    b -= NB_SENT;
    if (b < NB_WPREP) {  // W fp32 [k][n] -> bf16 transposed [n][k]
        int i = b * 256 + t;
        int l = i >> 14;
        int idx = i & (DIM * DIM - 1);
        int n = idx >> 7, k = idx & (DIM - 1);
        const float* wsrc = (l == 0) ? w1 : (l == 1) ? w2 : w3;
        wbt[i] = f2bf(wsrc[k * DIM + n]);
        return;
    }
    b -= NB_WPREP;
    {  // dual coarse histogram (dst>>7 and src>>7): chunk b covers 4096 edges
        for (int k = t; k < NBUCK; k += 256) { hh[k] = 0; hh2[k] = 0; }
        __syncthreads();
        int e0 = b * 4096;
        int e1 = min(e0 + 4096, N_EDGES);
        for (int i = e0 + t; i < e1; i += 256) {
            atomicAdd(&hh[dst[i] >> 7], 1);
            atomicAdd(&hh2[src[i] >> 7], 1);
        }
        __syncthreads();
        for (int k = t; k < NBUCK; k += 256) {
            GG[k * NB_HIST + b] = hh[k];
            GG[NG + k * NB_HIST + b] = hh2[k];
        }
    }
}

// ---------------- scan of GG (both sides concatenated) -> exclusive Gs ----------------
__global__ void k_scanA(const int* __restrict__ GG, int* __restrict__ Gs,
                        int* __restrict__ partials) {
    __shared__ int s[256];
    int t = threadIdx.x;
    int i = blockIdx.x * 256 + t;
    int v = (i < 2 * NG) ? GG[i] : 0;
    s[t] = v;
    __syncthreads();
    for (int off = 1; off < 256; off <<= 1) {
        int add = (t >= off) ? s[t - off] : 0;
        __syncthreads();
        s[t] += add;
        __syncthreads();
    }
    if (i < 2 * NG) Gs[i + 1] = s[t];
    if (t == 255) partials[blockIdx.x] = s[t];
}

__global__ void k_scanB(const int* __restrict__ partials, int* __restrict__ Gs) {
    __shared__ int s[256];
    int t = threadIdx.x;
    int p = 0;
    for (int j = t; j < (int)blockIdx.x; j += 256) p += partials[j];
    s[t] = p;
    __syncthreads();
    for (int off = 128; off > 0; off >>= 1) {
        if (t < off) s[t] += s[t + off];
        __syncthreads();
    }
    int prefix = s[0];
    int i = blockIdx.x * 256 + t;
    if (i < 2 * NG) Gs[i + 1] += prefix;
    if (blockIdx.x == 0 && t == 0) Gs[0] = 0;
}

// ---------------- pass 2: coarse scatter, dst side (Csrc,Cdl) + src side (Cls) ----------------
__global__ void k_pass2(const int* __restrict__ src, const int* __restrict__ dst,
                        const int* __restrict__ Gs, int* __restrict__ Csrc,
                        uchar_t* __restrict__ Cdl, uchar_t* __restrict__ Cls) {
    __shared__ int cur[NBUCK];
    __shared__ int cur2[NBUCK];
    int b = blockIdx.x;  // 391 blocks
    int t = threadIdx.x;
    for (int k = t; k < NBUCK; k += 256) {
        cur[k] = Gs[k * NB_HIST + b];
        cur2[k] = Gs[NG + k * NB_HIST + b] - N_EDGES;
    }
    __syncthreads();
    int e0 = b * 4096;
    int e1 = min(e0 + 4096, N_EDGES);
    for (int i = e0 + t; i < e1; i += 256) {
        int d = dst[i];
        int s = src[i];
        int slot = atomicAdd(&cur[d >> 7], 1);
        Csrc[slot] = s;
        Cdl[slot] = (uchar_t)(d & 127);
        int slot2 = atomicAdd(&cur2[s >> 7], 1);
        Cls[slot2] = (uchar_t)(s & 127);
    }
}

// ---------------- pass 3, dual partition:
// blocks [0,NBUCK): dst-side fine build (rowptr/pdeg/nd + esrc)
// blocks [NBUCK,2*NBUCK): src-side fine histogram -> ns ----------------
__global__ void k_fine(const int* __restrict__ Csrc, const uchar_t* __restrict__ Cdl,
                       const uchar_t* __restrict__ Cls, const int* __restrict__ Gs,
                       int* __restrict__ esrc, int* __restrict__ rowptr,
                       int* __restrict__ pdeg, float* __restrict__ ns,
                       float* __restrict__ nd) {
    __shared__ int hcnt[128];
    __shared__ int hstart[128];
    int b = blockIdx.x;
    int t = threadIdx.x;
    if (b < NBUCK) {  // dst side
        int k = b;
        int node0 = k * 128;
        int nn = min(128, N_NODES - node0);
        int S = Gs[k * NB_HIST];
        int E = Gs[(k + 1) * NB_HIST];
        if (t < 128) hcnt[t] = 0;
        __syncthreads();
        for (int i = S + t; i < E; i += 256) atomicAdd(&hcnt[Cdl[i]], 1);
        __syncthreads();
        if (t == 0) {
            int acc = 0;
            for (int n = 0; n < nn; ++n) {
                hstart[n] = acc;
                acc += (hcnt[n] + 3) & ~3;
            }
        }
        __syncthreads();
        int base = (k * BUCK_RESERVE + S + 3) & ~3;
        if (t < nn) {
            int node = node0 + t;
            rowptr[node] = base + hstart[t];
            pdeg[node] = (hcnt[t] + 3) & ~3;
            nd[node] = rsqrtf(fmaxf((float)hcnt[t], 1.0f));
        }
        __syncthreads();
        for (int i = S + t; i < E; i += 256) {
            int slot = atomicAdd(&hstart[Cdl[i]], 1);
            esrc[base + slot] = Csrc[i];
        }
    } else {  // src side -> ns
        int k = b - NBUCK;
        int node0 = k * 128;
        int nn = min(128, N_NODES - node0);
        int S = Gs[NG + k * NB_HIST] - N_EDGES;
        int E = Gs[NG + (k + 1) * NB_HIST] - N_EDGES;
        if (t < 128) hcnt[t] = 0;
        __syncthreads();
        for (int i = S + t; i < E; i += 256) atomicAdd(&hcnt[Cls[i]], 1);
        __syncthreads();
        if (t < nn)
            ns[node0 + t] = rsqrtf(fmaxf((float)hcnt[t], 1.0f));
        if (k == 0 && t == 0) ns[N_NODES] = 0.f;  // kills sentinel contributions
    }
}

// ---------------- fused embed gather + l0 prescale: bufA = bf16(embed[token]) * ns ----------------
__global__ void k_embed_ps(const int* __restrict__ tokens, const float* __restrict__ embed,
                           const float* __restrict__ ns, ushort_t* __restrict__ bufA) {
    int gid = blockIdx.x * 256 + threadIdx.x;  // 6250 blocks * 256 = N*16 exactly
    int node = gid >> 4, sub = gid & 15;
    float s = ns[node];
    const float* ep = embed + (size_t)tokens[node] * DIM + sub * 8;
    float4 a = *(const float4*)ep;
    float4 c = *(const float4*)(ep + 4);
    uint4 o;
    o.x = pack2(a.x * s, a.y * s);
    o.y = pack2(a.z * s, a.w * s);
    o.z = pack2(c.x * s, c.y * s);
    o.w = pack2(c.z * s, c.w * s);
    *(uint4*)(bufA + (size_t)node * DIM + sub * 8) = o;
}

// ---------------- prescale: x[v] = relu(fma(y,a,c)) * ns[v], bf16 (BN layers) ----------------
__global__ void k_prescale(const ushort_t* __restrict__ yin, const float* __restrict__ ns,
                           const float* __restrict__ bnsum, const float* __restrict__ bnsq,
                           const float* __restrict__ g, const float* __restrict__ be,
                           ushort_t* __restrict__ xout) {
    __shared__ float sa[DIM], sc[DIM];
    int t = threadIdx.x;
    if (t < DIM) {
        float mu = bnsum[t] * (1.0f / N_NODES);
        float var = bnsq[t] * (1.0f / N_NODES) - mu * mu;
        float rstd = rsqrtf(var + BN_EPS);
        float a = g[t] * rstd;
        sa[t] = a;
        sc[t] = be[t] - mu * a;
    }
    __syncthreads();
    int gid = blockIdx.x * 256 + t;  // 6250 blocks * 256 = N*16 exactly
    int node = gid >> 4, sub = gid & 15;
    float s = ns[node];
    uint4 u = *(const uint4*)(yin + (size_t)node * DIM + sub * 8);
    float v[8] = {bfl(u.x), bfh(u.x), bfl(u.y), bfh(u.y),
                  bfl(u.z), bfh(u.z), bfl(u.w), bfh(u.w)};
    const float* a = sa + sub * 8;
    const float* c = sc + sub * 8;
#pragma unroll
    for (int i = 0; i < 8; ++i) v[i] = fmaxf(fmaf(v[i], a[i], c[i]), 0.f) * s;
    uint4 o;
    o.x = pack2(v[0], v[1]); o.y = pack2(v[2], v[3]);
    o.z = pack2(v[4], v[5]); o.w = pack2(v[6], v[7]);
    *(uint4*)(xout + (size_t)node * DIM + sub * 8) = o;
}

// ---------------- FUSED pure-sum gather (2-node pipeline, idx prefetched one
// iteration ahead) -> LDS -> MFMA + BN stats. 128-thread blocks (2 waves,
// 32 nodes) for finer drain granularity / better CU refill. Barrier-free
// until the final stats reduce (A-tile and csum/csq rows are wave-private). ----------------
__global__ __launch_bounds__(128) void k_agggemm(const ushort_t* __restrict__ hs,
        const int* __restrict__ rowptr, const int* __restrict__ pdeg,
        const int* __restrict__ esrc, const float* __restrict__ nd,
        const ushort_t* __restrict__ wbt, const float* __restrict__ bias,
        ushort_t* __restrict__ y,
        float* __restrict__ bnsum, float* __restrict__ bnsq) {
    __shared__ ushort_t at[32 * AT_STRIDE];
    __shared__ float csum[2][DIM], csq[2][DIM];  // per-wave rows
    int tid = threadIdx.x;
    int wave = tid >> 6;  // 0..1
    int lane = tid & 63;
    // per-wave stats init (no barrier needed: rows are wave-private)
    csum[wave][lane] = 0.f;
    csum[wave][lane + 64] = 0.f;
    csq[wave][lane] = 0.f;
    csq[wave][lane + 64] = 0.f;

    int bnode = blockIdx.x * 32 + wave * 16;
    int off = lane * 2;

    // prefetch the wave's 16 row starts + padded degrees, serve via shfl
    int rpv = 0, pdv = 0;
    if (lane < 16) {
        int nnode = bnode + lane;
        if (nnode < N_NODES) { rpv = rowptr[nnode]; pdv = pdeg[nnode]; }
    }

#define LD2(s) (*(const uint_t*)(hs + (size_t)(s) * DIM + off))
#define ACC8(I0, I1, X0, Y0, X1, Y1)                                           \
    {                                                                          \
        uint_t u0 = LD2(I0.x), u1 = LD2(I0.y), u2 = LD2(I0.z), u3 = LD2(I0.w); \
        uint_t u4 = LD2(I1.x), u5 = LD2(I1.y), u6 = LD2(I1.z), u7 = LD2(I1.w); \
        X0 += bfl(u0); Y0 += bfh(u0); X1 += bfl(u1); Y1 += bfh(u1);            \
        X0 += bfl(u2); Y0 += bfh(u2); X1 += bfl(u3); Y1 += bfh(u3);            \
        X0 += bfl(u4); Y0 += bfh(u4); X1 += bfl(u5); Y1 += bfh(u5);            \
        X0 += bfl(u6); Y0 += bfh(u6); X1 += bfl(u7); Y1 += bfh(u7);            \
    }
#define ACC4(I0, X0, Y0, X1, Y1)                                               \
    {                                                                          \
        uint_t u0 = LD2(I0.x), u1 = LD2(I0.y), u2 = LD2(I0.z), u3 = LD2(I0.w); \
        X0 += bfl(u0); Y0 += bfh(u0); X1 += bfl(u1); Y1 += bfh(u1);            \
        X0 += bfl(u2); Y0 += bfh(u2); X1 += bfl(u3); Y1 += bfh(u3);            \
    }

    // ---- phase 1: gather, 2 nodes in flight, indices pipelined 1 iter ahead ----
    for (int i = 0; i < 16; i += 2) {
        int nodeA = bnode + i;
        int nodeB = bnode + i + 1;
        int eA = __shfl(rpv, i);
        int endA = eA + __shfl(pdv, i);
        int eB = __shfl(rpv, i + 1);
        int endB = eB + __shfl(pdv, i + 1);
        float xA0 = 0.f, yA0 = 0.f, xA1 = 0.f, yA1 = 0.f;
        float xB0 = 0.f, yB0 = 0.f, xB1 = 0.f, yB1 = 0.f;
        // joint main loop: 16 feature loads in flight; next iter's idx loads
        // issued under the feature-load latency (prefetch past row end is safe:
        // EPAD slack; values discarded on exit).
        if (eA + 8 <= endA && eB + 8 <= endB) {
            int4 cA0 = *(const int4*)(esrc + eA);
            int4 cA1 = *(const int4*)(esrc + eA + 4);
            int4 cB0 = *(const int4*)(esrc + eB);
            int4 cB1 = *(const int4*)(esrc + eB + 4);
            while (true) {
                int4 nA0 = *(const int4*)(esrc + eA + 8);
                int4 nA1 = *(const int4*)(esrc + eA + 12);
                int4 nB0 = *(const int4*)(esrc + eB + 8);
                int4 nB1 = *(const int4*)(esrc + eB + 12);
                ACC8(cA0, cA1, xA0, yA0, xA1, yA1);
                ACC8(cB0, cB1, xB0, yB0, xB1, yB1);
                eA += 8; eB += 8;
                if (!(eA + 8 <= endA && eB + 8 <= endB)) break;
                cA0 = nA0; cA1 = nA1; cB0 = nB0; cB1 = nB1;
            }
        }
        // drain A
        for (; eA + 8 <= endA; eA += 8) {
            int4 i0 = *(const int4*)(esrc + eA);
            int4 i1 = *(const int4*)(esrc + eA + 4);
            ACC8(i0, i1, xA0, yA0, xA1, yA1);
        }
        if (eA < endA) {  // exactly 4 (rows padded to x4)
            int4 i0 = *(const int4*)(esrc + eA);
            ACC4(i0, xA0, yA0, xA1, yA1);
        }
        // drain B
        for (; eB + 8 <= endB; eB += 8) {
            int4 i0 = *(const int4*)(esrc + eB);
            int4 i1 = *(const int4*)(esrc + eB + 4);
            ACC8(i0, i1, xB0, yB0, xB1, yB1);
        }
        if (eB < endB) {
            int4 i0 = *(const int4*)(esrc + eB);
            ACC4(i0, xB0, yB0, xB1, yB1);
        }
        // finalize both nodes
        uint_t ovA = 0u, ovB = 0u;
        if (nodeA < N_NODES) {
            float n = nd[nodeA];
            ovA = pack2((xA0 + xA1) * n, (yA0 + yA1) * n);
        }
        if (nodeB < N_NODES) {
            float n = nd[nodeB];
            ovB = pack2((xB0 + xB1) * n, (yB0 + yB1) * n);
        }
        *(uint_t*)&at[(wave * 16 + i) * AT_STRIDE + off] = ovA;
        *(uint_t*)&at[(wave * 16 + i + 1) * AT_STRIDE + off] = ovB;
    }
#undef ACC8
#undef ACC4
#undef LD2
    // NO barrier: each wave's MFMA reads only its own 16 LDS rows.

    // ---- phase 2: MFMA (D: col=lane&15, row=quad*4+reg) ----
    int m16 = lane & 15;
    int quad = lane >> 4;
    f32x4 acc[8];
#pragma unroll
    for (int nb = 0; nb < 8; ++nb) acc[nb] = (f32x4)(0.f);

    const ushort_t* ap = &at[(wave * 16 + m16) * AT_STRIDE + quad * 8];
#pragma unroll
    for (int k0b = 0; k0b < 4; ++k0b) {
        bf16x8 af = *(const bf16x8*)(ap + k0b * 32);
#pragma unroll
        for (int nb = 0; nb < 8; ++nb) {
            int ncol = nb * 16 + m16;
            bf16x8 bfg = *(const bf16x8*)(wbt + (size_t)ncol * DIM + k0b * 32 + quad * 8);
            acc[nb] = __builtin_amdgcn_mfma_f32_16x16x32_bf16(af, bfg, acc[nb], 0, 0, 0);
        }
    }

    // epilogue: bias, per-wave BN partial stats, bf16 store
#pragma unroll
    for (int nb = 0; nb < 8; ++nb) {
        int col = nb * 16 + m16;
        float bcol = bias[col];
        float ps = 0.f, pq = 0.f;
#pragma unroll
        for (int reg = 0; reg < 4; ++reg) {
            int r = bnode + quad * 4 + reg;
            if (r < N_NODES) {
                float v = acc[nb][reg] + bcol;
                ps += v; pq += v * v;
                y[(size_t)r * DIM + col] = f2bf(v);
            }
        }
        atomicAdd(&csum[wave][col], ps);
        atomicAdd(&csq[wave][col], pq);
    }
    __syncthreads();  // single barrier: cross-wave stats reduce
    if (tid < DIM) {
        atomicAdd(&bnsum[tid], csum[0][tid] + csum[1][tid]);
        atomicAdd(&bnsq[tid], csq[0][tid] + csq[1][tid]);
    }
}

// ---------------- pooling: fused layer-3 BN fold+apply + graph counts ----------------
#define POOL_NODES 128
__global__ void k_pool(const ushort_t* __restrict__ yin, const int* __restrict__ gids,
                       const float* __restrict__ bnsum, const float* __restrict__ bnsq,
                       const float* __restrict__ g, const float* __restrict__ be,
                       float* __restrict__ pool, int* __restrict__ cnt) {
    __shared__ int h[N_GRAPHS];
    int col = threadIdx.x;  // 128
    float mu = bnsum[col] * (1.0f / N_NODES);
    float var = bnsq[col] * (1.0f / N_NODES) - mu * mu;
    float rstd = rsqrtf(var + BN_EPS);
    float a = g[col] * rstd;
    float c = be[col] - mu * a;
    if (col < N_GRAPHS) h[col] = 0;
    __syncthreads();
    int base = blockIdx.x * POOL_NODES;
    int end = min(base + POOL_NODES, N_NODES);
    for (int n = base + col; n < end; n += 128) atomicAdd(&h[gids[n]], 1);
    __syncthreads();
    if (col < N_GRAPHS && h[col]) atomicAdd(&cnt[col], h[col]);
    float acc = 0.f;
    int cur = gids[base];
    for (int n = base; n < end; ++n) {
        int gg = gids[n];
        if (gg != cur) {
            atomicAdd(&pool[(size_t)cur * DIM + col], acc);
            acc = 0.f;
            cur = gg;
        }
        uint_t u = *(const uint_t*)(yin + (size_t)n * DIM + (col & ~1));
        float v = (col & 1) ? bfh(u) : bfl(u);
        acc += fmaxf(fmaf(v, a, c), 0.f);
    }
    atomicAdd(&pool[(size_t)cur * DIM + col], acc);
}

// ---------------- final FC (one block per graph) ----------------
__global__ void k_final(const float* __restrict__ pool, const int* __restrict__ cnt,
                        const float* __restrict__ fcW1, const float* __restrict__ fcb1,
                        const float* __restrict__ fcW2, const float* __restrict__ fcb2,
                        float* __restrict__ out) {
    __shared__ float hg[DIM];
    __shared__ float z[64];
    int g = blockIdx.x;
    int t = threadIdx.x;  // 128
    float cf = fmaxf((float)cnt[g], 1.0f);
    hg[t] = pool[(size_t)g * DIM + t] / cf;
    __syncthreads();
    if (t < 64) {
        float acc = fcb1[t];
        for (int k = 0; k < DIM; ++k)
            acc += hg[k] * fcW1[k * 64 + t];
        z[t] = fmaxf(acc, 0.f);
    }
    __syncthreads();
    if (t < 2) {
        float acc = fcb2[t];
        for (int k = 0; k < 64; ++k)
            acc += z[k] * fcW2[k * 2 + t];
        out[g * 2 + t] = acc;
    }
}

extern "C" void kernel_launch(void* const* d_in, const int* in_sizes, int n_in,
                              void* d_out, int out_size, void* d_ws, size_t ws_size,
                              hipStream_t stream) {
    const int* tokens = (const int*)d_in[0];
    const int* src = (const int*)d_in[1];
    const int* dst = (const int*)d_in[2];
    const int* gids = (const int*)d_in[3];
    const float* embed = (const float*)d_in[4];
    const float* W1 = (const float*)d_in[5];
    const float* b1 = (const float*)d_in[6];
    const float* g1 = (const float*)d_in[7];
    const float* be1 = (const float*)d_in[8];
    const float* W2 = (const float*)d_in[9];
    const float* b2 = (const float*)d_in[10];
    const float* g2 = (const float*)d_in[11];
    const float* be2 = (const float*)d_in[12];
    const float* W3 = (const float*)d_in[13];
    const float* b3 = (const float*)d_in[14];
    const float* g3 = (const float*)d_in[15];
    const float* be3 = (const float*)d_in[16];
    const float* fcW1 = (const float*)d_in[17];
    const float* fcb1 = (const float*)d_in[18];
    const float* fcW2 = (const float*)d_in[19];
    const float* fcb2 = (const float*)d_in[20];
    float* out = (float*)d_out;

    char* w = (char*)d_ws;
    auto alloc = [&](size_t bytes) {
        void* p = (void*)w;
        w += (bytes + 255) & ~(size_t)255;
        return p;
    };
    ushort_t* bufH = (ushort_t*)alloc((size_t)(N_NODES + 1) * DIM * 2);  // y2
    ushort_t* bufA = (ushort_t*)alloc((size_t)(N_NODES + 1) * DIM * 2);  // prescaled gather input
    ushort_t* bufY = (ushort_t*)alloc((size_t)(N_NODES + 1) * DIM * 2);  // y1 / y3
    int* esrc = (int*)alloc((size_t)EPAD * 4);
    int* rowptr = (int*)alloc((size_t)N_NODES * 4);
    int* pdeg = (int*)alloc((size_t)N_NODES * 4);
    float* ns = (float*)alloc((size_t)(N_NODES + 1) * 4);
    float* nd = (float*)alloc((size_t)N_NODES * 4);
    ushort_t* wbt = (ushort_t*)alloc(3 * DIM * DIM * 2);
    int* GG = (int*)alloc((size_t)(2 * NG) * 4);
    int* Gs = (int*)alloc((size_t)(2 * NG + 1) * 4);
    int* partials = (int*)alloc(4096 * 4);
    int* Csrc = (int*)alloc((size_t)N_EDGES * 4);
    uchar_t* Cdl = (uchar_t*)alloc((size_t)N_EDGES);
    uchar_t* Cls = (uchar_t*)alloc((size_t)N_EDGES);
    // zeroed region (contiguous)
    char* zstart = w;
    float* bnsum = (float*)alloc(3 * DIM * 4);
    float* bnsq = (float*)alloc(3 * DIM * 4);
    float* pool = (float*)alloc((size_t)N_GRAPHS * DIM * 4);
    int* cnt = (int*)alloc((size_t)N_GRAPHS * 4);
    int zwords = (int)((size_t)(w - zstart) / 4);

    k_zero<<<(zwords + 255) / 256, 256, 0, stream>>>((int*)zstart, zwords);
    k_front<<<NB_SENT + NB_WPREP + NB_HIST, 256, 0, stream>>>(
        src, dst, bufA, esrc, W1, W2, W3, wbt, GG);
    k_scanA<<<NB_SCANG2, 256, 0, stream>>>(GG, Gs, partials);
    k_scanB<<<NB_SCANG2, 256, 0, stream>>>(partials, Gs);
    k_pass2<<<NB_HIST, 256, 0, stream>>>(src, dst, Gs, Csrc, Cdl, Cls);
    k_fine<<<2 * NBUCK, 256, 0, stream>>>(Csrc, Cdl, Cls, Gs, esrc, rowptr, pdeg, ns, nd);

    int nb_fused = (N_NODES + 31) / 32;  // 128-thread blocks, 32 nodes each
    int nb_ps = 6250;                    // N*16/256

    // l=0: fused embed+prescale -> bufA; gather bufA -> y1 in bufY
    k_embed_ps<<<nb_ps, 256, 0, stream>>>(tokens, embed, ns, bufA);
    k_agggemm<<<nb_fused, 128, 0, stream>>>(bufA, rowptr, pdeg, esrc, nd,
                                            wbt, b1, bufY, bnsum, bnsq);
    // l=1: prescale bufY (BN stats1) -> bufA; gather -> y2 in bufH
    k_prescale<<<nb_ps, 256, 0, stream>>>(bufY, ns, bnsum, bnsq, g1, be1, bufA);
    k_agggemm<<<nb_fused, 128, 0, stream>>>(bufA, rowptr, pdeg, esrc, nd,
                                            wbt + (size_t)DIM * DIM, b2, bufH,
                                            bnsum + DIM, bnsq + DIM);
    // l=2: prescale bufH (BN stats2) -> bufA; gather -> y3 in bufY
    k_prescale<<<nb_ps, 256, 0, stream>>>(bufH, ns, bnsum + DIM, bnsq + DIM, g2, be2, bufA);
    k_agggemm<<<nb_fused, 128, 0, stream>>>(bufA, rowptr, pdeg, esrc, nd,
                                            wbt + (size_t)2 * DIM * DIM, b3, bufY,
                                            bnsum + 2 * DIM, bnsq + 2 * DIM);

    k_pool<<<(N_NODES + POOL_NODES - 1) / POOL_NODES, DIM, 0, stream>>>(
        bufY, gids, bnsum + 2 * DIM, bnsq + 2 * DIM, g3, be3, pool, cnt);
    k_final<<<N_GRAPHS, DIM, 0, stream>>>(pool, cnt, fcW1, fcb1, fcW2, fcb2, out);
}

// Round 21
// 657.060 us; speedup vs baseline: 1.1341x; 1.1341x over previous
//
#include <hip/hip_runtime.h>

#define N_NODES 100000
#define N_EDGES 1600000
#define N_GRAPHS 64
#define DIM 128
#define BN_EPS 1e-5f
#define EPAD 2000000          // sentinel-filled esrc capacity (needs 1,903,419)

#define NB_SENT 977           // esrc sentinel fill, 8 per thread
#define NB_WPREP 192          // 3*128*128/256
#define NB_HIST 391           // coarse hist: 391 chunks * 4096 edges
#define NBUCK 782             // coarse buckets = id>>7 (100000/128)
#define NG (NBUCK * NB_HIST)  // per-side count-matrix size = 305762
#define NB_SCANG2 2389        // ceil(2*NG/256)
#define BUCK_RESERVE 388      // cnt + 128*3 pad + 4 align slack

#define AT_STRIDE 136  // 128 + 8 pad: 2-way-only LDS bank aliasing

typedef unsigned short ushort_t;
typedef unsigned char uchar_t;
typedef unsigned int uint_t;
typedef __attribute__((ext_vector_type(8))) short bf16x8;
typedef __attribute__((ext_vector_type(4))) float f32x4;

__device__ __forceinline__ float bfl(uint_t u) {
    union { uint_t i; float f; } v; v.i = u << 16; return v.f;
}
__device__ __forceinline__ float bfh(uint_t u) {
    union { uint_t i; float f; } v; v.i = u & 0xffff0000u; return v.f;
}
__device__ __forceinline__ ushort_t f2bf(float f) {
    union { float f; uint_t i; } v; v.f = f;
    uint_t x = v.i;
    return (ushort_t)((x + 0x7fffu + ((x >> 16) & 1u)) >> 16);
}
__device__ __forceinline__ uint_t pack2(float lo, float hi) {
    return ((uint_t)f2bf(hi) << 16) | (uint_t)f2bf(lo);
}

// ---------------- zero scratch ----------------
__global__ void k_zero(int* __restrict__ p, int n) {
    int i = blockIdx.x * blockDim.x + threadIdx.x;
    if (i < n) p[i] = 0;
}

// ---------------- front mega-kernel: {sentinel | wprep | dual coarse-hist} ----------------
__global__ void k_front(const int* __restrict__ src, const int* __restrict__ dst,
                        ushort_t* __restrict__ bufA, int* __restrict__ esrc,
                        const float* __restrict__ w1, const float* __restrict__ w2,
                        const float* __restrict__ w3, ushort_t* __restrict__ wbt,
                        int* __restrict__ GG) {
    __shared__ int hh[NBUCK];
    __shared__ int hh2[NBUCK];
    int b = blockIdx.x;
    int t = threadIdx.x;
    if (b < NB_SENT) {  // esrc sentinel fill + zero bufA sentinel feature row
        int i0 = (b * 256 + t) * 8;
        int4 sv = make_int4(N_NODES, N_NODES, N_NODES, N_NODES);
        if (i0 + 8 <= EPAD) {
            *(int4*)(esrc + i0) = sv;
            *(int4*)(esrc + i0 + 4) = sv;
        } else {
            for (int i = i0; i < EPAD; ++i) esrc[i] = N_NODES;
        }
        if (b == 0 && t < 64)
            ((uint_t*)(bufA + (size_t)N_NODES * DIM))[t] = 0u;
        return;
    }
    b -= NB_SENT;
    if (b < NB_WPREP) {  // W fp32 [k][n] -> bf16 transposed [n][k]
        int i = b * 256 + t;
        int l = i >> 14;
        int idx = i & (DIM * DIM - 1);
        int n = idx >> 7, k = idx & (DIM - 1);
        const float* wsrc = (l == 0) ? w1 : (l == 1) ? w2 : w3;
        wbt[i] = f2bf(wsrc[k * DIM + n]);
        return;
    }
    b -= NB_WPREP;
    {  // dual coarse histogram (dst>>7 and src>>7): chunk b covers 4096 edges
        for (int k = t; k < NBUCK; k += 256) { hh[k] = 0; hh2[k] = 0; }
        __syncthreads();
        int e0 = b * 4096;
        int e1 = min(e0 + 4096, N_EDGES);
        for (int i = e0 + t; i < e1; i += 256) {
            atomicAdd(&hh[dst[i] >> 7], 1);
            atomicAdd(&hh2[src[i] >> 7], 1);
        }
        __syncthreads();
        for (int k = t; k < NBUCK; k += 256) {
            GG[k * NB_HIST + b] = hh[k];
            GG[NG + k * NB_HIST + b] = hh2[k];
        }
    }
}

// ---------------- scan of GG (both sides concatenated) -> exclusive Gs ----------------
__global__ void k_scanA(const int* __restrict__ GG, int* __restrict__ Gs,
                        int* __restrict__ partials) {
    __shared__ int s[256];
    int t = threadIdx.x;
    int i = blockIdx.x * 256 + t;
    int v = (i < 2 * NG) ? GG[i] : 0;
    s[t] = v;
    __syncthreads();
    for (int off = 1; off < 256; off <<= 1) {
        int add = (t >= off) ? s[t - off] : 0;
        __syncthreads();
        s[t] += add;
        __syncthreads();
    }
    if (i < 2 * NG) Gs[i + 1] = s[t];
    if (t == 255) partials[blockIdx.x] = s[t];
}

__global__ void k_scanB(const int* __restrict__ partials, int* __restrict__ Gs) {
    __shared__ int s[256];
    int t = threadIdx.x;
    int p = 0;
    for (int j = t; j < (int)blockIdx.x; j += 256) p += partials[j];
    s[t] = p;
    __syncthreads();
    for (int off = 128; off > 0; off >>= 1) {
        if (t < off) s[t] += s[t + off];
        __syncthreads();
    }
    int prefix = s[0];
    int i = blockIdx.x * 256 + t;
    if (i < 2 * NG) Gs[i + 1] += prefix;
    if (blockIdx.x == 0 && t == 0) Gs[0] = 0;
}

// ---------------- pass 2: coarse scatter, dst side (Csrc,Cdl) + src side (Cls) ----------------
__global__ void k_pass2(const int* __restrict__ src, const int* __restrict__ dst,
                        const int* __restrict__ Gs, int* __restrict__ Csrc,
                        uchar_t* __restrict__ Cdl, uchar_t* __restrict__ Cls) {
    __shared__ int cur[NBUCK];
    __shared__ int cur2[NBUCK];
    int b = blockIdx.x;  // 391 blocks
    int t = threadIdx.x;
    for (int k = t; k < NBUCK; k += 256) {
        cur[k] = Gs[k * NB_HIST + b];
        cur2[k] = Gs[NG + k * NB_HIST + b] - N_EDGES;
    }
    __syncthreads();
    int e0 = b * 4096;
    int e1 = min(e0 + 4096, N_EDGES);
    for (int i = e0 + t; i < e1; i += 256) {
        int d = dst[i];
        int s = src[i];
        int slot = atomicAdd(&cur[d >> 7], 1);
        Csrc[slot] = s;
        Cdl[slot] = (uchar_t)(d & 127);
        int slot2 = atomicAdd(&cur2[s >> 7], 1);
        Cls[slot2] = (uchar_t)(s & 127);
    }
}

// ---------------- pass 3, dual partition:
// blocks [0,NBUCK): dst-side fine build (rowptr/pdeg/nd + esrc)
// blocks [NBUCK,2*NBUCK): src-side fine histogram -> ns ----------------
__global__ void k_fine(const int* __restrict__ Csrc, const uchar_t* __restrict__ Cdl,
                       const uchar_t* __restrict__ Cls, const int* __restrict__ Gs,
                       int* __restrict__ esrc, int* __restrict__ rowptr,
                       int* __restrict__ pdeg, float* __restrict__ ns,
                       float* __restrict__ nd) {
    __shared__ int hcnt[128];
    __shared__ int hstart[128];
    int b = blockIdx.x;
    int t = threadIdx.x;
    if (b < NBUCK) {  // dst side
        int k = b;
        int node0 = k * 128;
        int nn = min(128, N_NODES - node0);
        int S = Gs[k * NB_HIST];
        int E = Gs[(k + 1) * NB_HIST];
        if (t < 128) hcnt[t] = 0;
        __syncthreads();
        for (int i = S + t; i < E; i += 256) atomicAdd(&hcnt[Cdl[i]], 1);
        __syncthreads();
        if (t == 0) {
            int acc = 0;
            for (int n = 0; n < nn; ++n) {
                hstart[n] = acc;
                acc += (hcnt[n] + 3) & ~3;
            }
        }
        __syncthreads();
        int base = (k * BUCK_RESERVE + S + 3) & ~3;
        if (t < nn) {
            int node = node0 + t;
            rowptr[node] = base + hstart[t];
            pdeg[node] = (hcnt[t] + 3) & ~3;
            nd[node] = rsqrtf(fmaxf((float)hcnt[t], 1.0f));
        }
        __syncthreads();
        for (int i = S + t; i < E; i += 256) {
            int slot = atomicAdd(&hstart[Cdl[i]], 1);
            esrc[base + slot] = Csrc[i];
        }
    } else {  // src side -> ns
        int k = b - NBUCK;
        int node0 = k * 128;
        int nn = min(128, N_NODES - node0);
        int S = Gs[NG + k * NB_HIST] - N_EDGES;
        int E = Gs[NG + (k + 1) * NB_HIST] - N_EDGES;
        if (t < 128) hcnt[t] = 0;
        __syncthreads();
        for (int i = S + t; i < E; i += 256) atomicAdd(&hcnt[Cls[i]], 1);
        __syncthreads();
        if (t < nn)
            ns[node0 + t] = rsqrtf(fmaxf((float)hcnt[t], 1.0f));
        if (k == 0 && t == 0) ns[N_NODES] = 0.f;  // kills sentinel contributions
    }
}

// ---------------- fused embed gather + l0 prescale: bufA = bf16(embed[token]) * ns ----------------
__global__ void k_embed_ps(const int* __restrict__ tokens, const float* __restrict__ embed,
                           const float* __restrict__ ns, ushort_t* __restrict__ bufA) {
    int gid = blockIdx.x * 256 + threadIdx.x;  // 6250 blocks * 256 = N*16 exactly
    int node = gid >> 4, sub = gid & 15;
    float s = ns[node];
    const float* ep = embed + (size_t)tokens[node] * DIM + sub * 8;
    float4 a = *(const float4*)ep;
    float4 c = *(const float4*)(ep + 4);
    uint4 o;
    o.x = pack2(a.x * s, a.y * s);
    o.y = pack2(a.z * s, a.w * s);
    o.z = pack2(c.x * s, c.y * s);
    o.w = pack2(c.z * s, c.w * s);
    *(uint4*)(bufA + (size_t)node * DIM + sub * 8) = o;
}

// ---------------- prescale: x[v] = relu(fma(y,a,c)) * ns[v], bf16 (BN layers) ----------------
__global__ void k_prescale(const ushort_t* __restrict__ yin, const float* __restrict__ ns,
                           const float* __restrict__ bnsum, const float* __restrict__ bnsq,
                           const float* __restrict__ g, const float* __restrict__ be,
                           ushort_t* __restrict__ xout) {
    __shared__ float sa[DIM], sc[DIM];
    int t = threadIdx.x;
    if (t < DIM) {
        float mu = bnsum[t] * (1.0f / N_NODES);
        float var = bnsq[t] * (1.0f / N_NODES) - mu * mu;
        float rstd = rsqrtf(var + BN_EPS);
        float a = g[t] * rstd;
        sa[t] = a;
        sc[t] = be[t] - mu * a;
    }
    __syncthreads();
    int gid = blockIdx.x * 256 + t;  // 6250 blocks * 256 = N*16 exactly
    int node = gid >> 4, sub = gid & 15;
    float s = ns[node];
    uint4 u = *(const uint4*)(yin + (size_t)node * DIM + sub * 8);
    float v[8] = {bfl(u.x), bfh(u.x), bfl(u.y), bfh(u.y),
                  bfl(u.z), bfh(u.z), bfl(u.w), bfh(u.w)};
    const float* a = sa + sub * 8;
    const float* c = sc + sub * 8;
#pragma unroll
    for (int i = 0; i < 8; ++i) v[i] = fmaxf(fmaf(v[i], a[i], c[i]), 0.f) * s;
    uint4 o;
    o.x = pack2(v[0], v[1]); o.y = pack2(v[2], v[3]);
    o.z = pack2(v[4], v[5]); o.w = pack2(v[6], v[7]);
    *(uint4*)(xout + (size_t)node * DIM + sub * 8) = o;
}

// ---------------- FUSED pure-sum gather (2-node pipeline, idx prefetched one
// iteration ahead) -> LDS -> MFMA + BN stats. 256-thread blocks (4 waves,
// 64 nodes — proven best). Barrier-free until the final stats reduce
// (A-tile and csum/csq rows are wave-private). ----------------
__global__ __launch_bounds__(256) void k_agggemm(const ushort_t* __restrict__ hs,
        const int* __restrict__ rowptr, const int* __restrict__ pdeg,
        const int* __restrict__ esrc, const float* __restrict__ nd,
        const ushort_t* __restrict__ wbt, const float* __restrict__ bias,
        ushort_t* __restrict__ y,
        float* __restrict__ bnsum, float* __restrict__ bnsq) {
    __shared__ ushort_t at[64 * AT_STRIDE];
    __shared__ float csum[4][DIM], csq[4][DIM];  // per-wave rows
    int tid = threadIdx.x;
    int wave = tid >> 6;
    int lane = tid & 63;
    // per-wave stats init (no barrier needed: rows are wave-private)
    csum[wave][lane] = 0.f;
    csum[wave][lane + 64] = 0.f;
    csq[wave][lane] = 0.f;
    csq[wave][lane + 64] = 0.f;

    int bnode = blockIdx.x * 64 + wave * 16;
    int off = lane * 2;

    // prefetch the wave's 16 row starts + padded degrees, serve via shfl
    int rpv = 0, pdv = 0;
    if (lane < 16) {
        int nnode = bnode + lane;
        if (nnode < N_NODES) { rpv = rowptr[nnode]; pdv = pdeg[nnode]; }
    }

#define LD2(s) (*(const uint_t*)(hs + (size_t)(s) * DIM + off))
#define ACC8(I0, I1, X0, Y0, X1, Y1)                                           \
    {                                                                          \
        uint_t u0 = LD2(I0.x), u1 = LD2(I0.y), u2 = LD2(I0.z), u3 = LD2(I0.w); \
        uint_t u4 = LD2(I1.x), u5 = LD2(I1.y), u6 = LD2(I1.z), u7 = LD2(I1.w); \
        X0 += bfl(u0); Y0 += bfh(u0); X1 += bfl(u1); Y1 += bfh(u1);            \
        X0 += bfl(u2); Y0 += bfh(u2); X1 += bfl(u3); Y1 += bfh(u3);            \
        X0 += bfl(u4); Y0 += bfh(u4); X1 += bfl(u5); Y1 += bfh(u5);            \
        X0 += bfl(u6); Y0 += bfh(u6); X1 += bfl(u7); Y1 += bfh(u7);            \
    }
#define ACC4(I0, X0, Y0, X1, Y1)                                               \
    {                                                                          \
        uint_t u0 = LD2(I0.x), u1 = LD2(I0.y), u2 = LD2(I0.z), u3 = LD2(I0.w); \
        X0 += bfl(u0); Y0 += bfh(u0); X1 += bfl(u1); Y1 += bfh(u1);            \
        X0 += bfl(u2); Y0 += bfh(u2); X1 += bfl(u3); Y1 += bfh(u3);            \
    }

    // ---- phase 1: gather, 2 nodes in flight, indices pipelined 1 iter ahead ----
    for (int i = 0; i < 16; i += 2) {
        int nodeA = bnode + i;
        int nodeB = bnode + i + 1;
        int eA = __shfl(rpv, i);
        int endA = eA + __shfl(pdv, i);
        int eB = __shfl(rpv, i + 1);
        int endB = eB + __shfl(pdv, i + 1);
        float xA0 = 0.f, yA0 = 0.f, xA1 = 0.f, yA1 = 0.f;
        float xB0 = 0.f, yB0 = 0.f, xB1 = 0.f, yB1 = 0.f;
        // joint main loop: 16 feature loads in flight; next iter's idx loads
        // issued under the feature-load latency (prefetch past row end is safe:
        // EPAD slack; values discarded on exit).
        if (eA + 8 <= endA && eB + 8 <= endB) {
            int4 cA0 = *(const int4*)(esrc + eA);
            int4 cA1 = *(const int4*)(esrc + eA + 4);
            int4 cB0 = *(const int4*)(esrc + eB);
            int4 cB1 = *(const int4*)(esrc + eB + 4);
            while (true) {
                int4 nA0 = *(const int4*)(esrc + eA + 8);
                int4 nA1 = *(const int4*)(esrc + eA + 12);
                int4 nB0 = *(const int4*)(esrc + eB + 8);
                int4 nB1 = *(const int4*)(esrc + eB + 12);
                ACC8(cA0, cA1, xA0, yA0, xA1, yA1);
                ACC8(cB0, cB1, xB0, yB0, xB1, yB1);
                eA += 8; eB += 8;
                if (!(eA + 8 <= endA && eB + 8 <= endB)) break;
                cA0 = nA0; cA1 = nA1; cB0 = nB0; cB1 = nB1;
            }
        }
        // drain A
        for (; eA + 8 <= endA; eA += 8) {
            int4 i0 = *(const int4*)(esrc + eA);
            int4 i1 = *(const int4*)(esrc + eA + 4);
            ACC8(i0, i1, xA0, yA0, xA1, yA1);
        }
        if (eA < endA) {  // exactly 4 (rows padded to x4)
            int4 i0 = *(const int4*)(esrc + eA);
            ACC4(i0, xA0, yA0, xA1, yA1);
        }
        // drain B
        for (; eB + 8 <= endB; eB += 8) {
            int4 i0 = *(const int4*)(esrc + eB);
            int4 i1 = *(const int4*)(esrc + eB + 4);
            ACC8(i0, i1, xB0, yB0, xB1, yB1);
        }
        if (eB < endB) {
            int4 i0 = *(const int4*)(esrc + eB);
            ACC4(i0, xB0, yB0, xB1, yB1);
        }
        // finalize both nodes
        uint_t ovA = 0u, ovB = 0u;
        if (nodeA < N_NODES) {
            float n = nd[nodeA];
            ovA = pack2((xA0 + xA1) * n, (yA0 + yA1) * n);
        }
        if (nodeB < N_NODES) {
            float n = nd[nodeB];
            ovB = pack2((xB0 + xB1) * n, (yB0 + yB1) * n);
        }
        *(uint_t*)&at[(wave * 16 + i) * AT_STRIDE + off] = ovA;
        *(uint_t*)&at[(wave * 16 + i + 1) * AT_STRIDE + off] = ovB;
    }
#undef ACC8
#undef ACC4
#undef LD2
    // NO barrier: each wave's MFMA reads only its own 16 LDS rows.

    // ---- phase 2: MFMA (D: col=lane&15, row=quad*4+reg) ----
    int m16 = lane & 15;
    int quad = lane >> 4;
    f32x4 acc[8];
#pragma unroll
    for (int nb = 0; nb < 8; ++nb) acc[nb] = (f32x4)(0.f);

    const ushort_t* ap = &at[(wave * 16 + m16) * AT_STRIDE + quad * 8];
#pragma unroll
    for (int k0b = 0; k0b < 4; ++k0b) {
        bf16x8 af = *(const bf16x8*)(ap + k0b * 32);
#pragma unroll
        for (int nb = 0; nb < 8; ++nb) {
            int ncol = nb * 16 + m16;
            bf16x8 bfg = *(const bf16x8*)(wbt + (size_t)ncol * DIM + k0b * 32 + quad * 8);
            acc[nb] = __builtin_amdgcn_mfma_f32_16x16x32_bf16(af, bfg, acc[nb], 0, 0, 0);
        }
    }

    // epilogue: bias, per-wave BN partial stats, bf16 store
#pragma unroll
    for (int nb = 0; nb < 8; ++nb) {
        int col = nb * 16 + m16;
        float bcol = bias[col];
        float ps = 0.f, pq = 0.f;
#pragma unroll
        for (int reg = 0; reg < 4; ++reg) {
            int r = bnode + quad * 4 + reg;
            if (r < N_NODES) {
                float v = acc[nb][reg] + bcol;
                ps += v; pq += v * v;
                y[(size_t)r * DIM + col] = f2bf(v);
            }
        }
        atomicAdd(&csum[wave][col], ps);
        atomicAdd(&csq[wave][col], pq);
    }
    __syncthreads();  // single barrier: cross-wave stats reduce
    if (tid < DIM) {
        float s = csum[0][tid] + csum[1][tid] + csum[2][tid] + csum[3][tid];
        float q = csq[0][tid] + csq[1][tid] + csq[2][tid] + csq[3][tid];
        atomicAdd(&bnsum[tid], s);
        atomicAdd(&bnsq[tid], q);
    }
}

// ---------------- pooling: fused layer-3 BN fold+apply + graph counts ----------------
#define POOL_NODES 128
__global__ void k_pool(const ushort_t* __restrict__ yin, const int* __restrict__ gids,
                       const float* __restrict__ bnsum, const float* __restrict__ bnsq,
                       const float* __restrict__ g, const float* __restrict__ be,
                       float* __restrict__ pool, int* __restrict__ cnt) {
    __shared__ int h[N_GRAPHS];
    int col = threadIdx.x;  // 128
    float mu = bnsum[col] * (1.0f / N_NODES);
    float var = bnsq[col] * (1.0f / N_NODES) - mu * mu;
    float rstd = rsqrtf(var + BN_EPS);
    float a = g[col] * rstd;
    float c = be[col] - mu * a;
    if (col < N_GRAPHS) h[col] = 0;
    __syncthreads();
    int base = blockIdx.x * POOL_NODES;
    int end = min(base + POOL_NODES, N_NODES);
    for (int n = base + col; n < end; n += 128) atomicAdd(&h[gids[n]], 1);
    __syncthreads();
    if (col < N_GRAPHS && h[col]) atomicAdd(&cnt[col], h[col]);
    float acc = 0.f;
    int cur = gids[base];
    for (int n = base; n < end; ++n) {
        int gg = gids[n];
        if (gg != cur) {
            atomicAdd(&pool[(size_t)cur * DIM + col], acc);
            acc = 0.f;
            cur = gg;
        }
        uint_t u = *(const uint_t*)(yin + (size_t)n * DIM + (col & ~1));
        float v = (col & 1) ? bfh(u) : bfl(u);
        acc += fmaxf(fmaf(v, a, c), 0.f);
    }
    atomicAdd(&pool[(size_t)cur * DIM + col], acc);
}

// ---------------- final FC (one block per graph) ----------------
__global__ void k_final(const float* __restrict__ pool, const int* __restrict__ cnt,
                        const float* __restrict__ fcW1, const float* __restrict__ fcb1,
                        const float* __restrict__ fcW2, const float* __restrict__ fcb2,
                        float* __restrict__ out) {
    __shared__ float hg[DIM];
    __shared__ float z[64];
    int g = blockIdx.x;
    int t = threadIdx.x;  // 128
    float cf = fmaxf((float)cnt[g], 1.0f);
    hg[t] = pool[(size_t)g * DIM + t] / cf;
    __syncthreads();
    if (t < 64) {
        float acc = fcb1[t];
        for (int k = 0; k < DIM; ++k)
            acc += hg[k] * fcW1[k * 64 + t];
        z[t] = fmaxf(acc, 0.f);
    }
    __syncthreads();
    if (t < 2) {
        float acc = fcb2[t];
        for (int k = 0; k < 64; ++k)
            acc += z[k] * fcW2[k * 2 + t];
        out[g * 2 + t] = acc;
    }
}

extern "C" void kernel_launch(void* const* d_in, const int* in_sizes, int n_in,
                              void* d_out, int out_size, void* d_ws, size_t ws_size,
                              hipStream_t stream) {
    const int* tokens = (const int*)d_in[0];
    const int* src = (const int*)d_in[1];
    const int* dst = (const int*)d_in[2];
    const int* gids = (const int*)d_in[3];
    const float* embed = (const float*)d_in[4];
    const float* W1 = (const float*)d_in[5];
    const float* b1 = (const float*)d_in[6];
    const float* g1 = (const float*)d_in[7];
    const float* be1 = (const float*)d_in[8];
    const float* W2 = (const float*)d_in[9];
    const float* b2 = (const float*)d_in[10];
    const float* g2 = (const float*)d_in[11];
    const float* be2 = (const float*)d_in[12];
    const float* W3 = (const float*)d_in[13];
    const float* b3 = (const float*)d_in[14];
    const float* g3 = (const float*)d_in[15];
    const float* be3 = (const float*)d_in[16];
    const float* fcW1 = (const float*)d_in[17];
    const float* fcb1 = (const float*)d_in[18];
    const float* fcW2 = (const float*)d_in[19];
    const float* fcb2 = (const float*)d_in[20];
    float* out = (float*)d_out;

    char* w = (char*)d_ws;
    auto alloc = [&](size_t bytes) {
        void* p = (void*)w;
        w += (bytes + 255) & ~(size_t)255;
        return p;
    };
    ushort_t* bufH = (ushort_t*)alloc((size_t)(N_NODES + 1) * DIM * 2);  // y2
    ushort_t* bufA = (ushort_t*)alloc((size_t)(N_NODES + 1) * DIM * 2);  // prescaled gather input
    ushort_t* bufY = (ushort_t*)alloc((size_t)(N_NODES + 1) * DIM * 2);  // y1 / y3
    int* esrc = (int*)alloc((size_t)EPAD * 4);
    int* rowptr = (int*)alloc((size_t)N_NODES * 4);
    int* pdeg = (int*)alloc((size_t)N_NODES * 4);
    float* ns = (float*)alloc((size_t)(N_NODES + 1) * 4);
    float* nd = (float*)alloc((size_t)N_NODES * 4);
    ushort_t* wbt = (ushort_t*)alloc(3 * DIM * DIM * 2);
    int* GG = (int*)alloc((size_t)(2 * NG) * 4);
    int* Gs = (int*)alloc((size_t)(2 * NG + 1) * 4);
    int* partials = (int*)alloc(4096 * 4);
    int* Csrc = (int*)alloc((size_t)N_EDGES * 4);
    uchar_t* Cdl = (uchar_t*)alloc((size_t)N_EDGES);
    uchar_t* Cls = (uchar_t*)alloc((size_t)N_EDGES);
    // zeroed region (contiguous)
    char* zstart = w;
    float* bnsum = (float*)alloc(3 * DIM * 4);
    float* bnsq = (float*)alloc(3 * DIM * 4);
    float* pool = (float*)alloc((size_t)N_GRAPHS * DIM * 4);
    int* cnt = (int*)alloc((size_t)N_GRAPHS * 4);
    int zwords = (int)((size_t)(w - zstart) / 4);

    k_zero<<<(zwords + 255) / 256, 256, 0, stream>>>((int*)zstart, zwords);
    k_front<<<NB_SENT + NB_WPREP + NB_HIST, 256, 0, stream>>>(
        src, dst, bufA, esrc, W1, W2, W3, wbt, GG);
    k_scanA<<<NB_SCANG2, 256, 0, stream>>>(GG, Gs, partials);
    k_scanB<<<NB_SCANG2, 256, 0, stream>>>(partials, Gs);
    k_pass2<<<NB_HIST, 256, 0, stream>>>(src, dst, Gs, Csrc, Cdl, Cls);
    k_fine<<<2 * NBUCK, 256, 0, stream>>>(Csrc, Cdl, Cls, Gs, esrc, rowptr, pdeg, ns, nd);

    int nb_fused = (N_NODES + 63) / 64;  // 256-thread blocks, 64 nodes each
    int nb_ps = 6250;                    // N*16/256

    // l=0: fused embed+prescale -> bufA; gather bufA -> y1 in bufY
    k_embed_ps<<<nb_ps, 256, 0, stream>>>(tokens, embed, ns, bufA);
    k_agggemm<<<nb_fused, 256, 0, stream>>>(bufA, rowptr, pdeg, esrc, nd,
                                            wbt, b1, bufY, bnsum, bnsq);
    // l=1: prescale bufY (BN stats1) -> bufA; gather -> y2 in bufH
    k_prescale<<<nb_ps, 256, 0, stream>>>(bufY, ns, bnsum, bnsq, g1, be1, bufA);
    k_agggemm<<<nb_fused, 256, 0, stream>>>(bufA, rowptr, pdeg, esrc, nd,
                                            wbt + (size_t)DIM * DIM, b2, bufH,
                                            bnsum + DIM, bnsq + DIM);
    // l=2: prescale bufH (BN stats2) -> bufA; gather -> y3 in bufY
    k_prescale<<<nb_ps, 256, 0, stream>>>(bufH, ns, bnsum + DIM, bnsq + DIM, g2, be2, bufA);
    k_agggemm<<<nb_fused, 256, 0, stream>>>(bufA, rowptr, pdeg, esrc, nd,
                                            wbt + (size_t)2 * DIM * DIM, b3, bufY,
                                            bnsum + 2 * DIM, bnsq + 2 * DIM);

    k_pool<<<(N_NODES + POOL_NODES - 1) / POOL_NODES, DIM, 0, stream>>>(
        bufY, gids, bnsum + 2 * DIM, bnsq + 2 * DIM, g3, be3, pool, cnt);
    k_final<<<N_GRAPHS, DIM, 0, stream>>>(pool, cnt, fcW1, fcb1, fcW2, fcb2, out);
}

// Round 22
// 655.611 us; speedup vs baseline: 1.1366x; 1.0022x over previous
//
#include <hip/hip_runtime.h>

#define N_NODES 100000
#define N_EDGES 1600000
#define N_GRAPHS 64
#define DIM 128
#define BN_EPS 1e-5f
#define EPAD 2000000          // sentinel-filled esrc capacity (needs 1,903,419)

#define NB_SENT 977           // esrc sentinel fill, 8 per thread
#define NB_WPREP 192          // 3*128*128/256
#define NB_HIST 391           // coarse hist: 391 chunks * 4096 edges
#define NB_ZERO 40            // zero scratch: 40*256 = 10240 words >= zwords
#define NBUCK 782             // coarse buckets = id>>7 (100000/128)
#define NG (NBUCK * NB_HIST)  // per-side count-matrix size = 305762
#define NB_SCANG2 2389        // ceil(2*NG/256)
#define BUCK_RESERVE 388      // cnt + 128*3 pad + 4 align slack

#define AT_STRIDE 136  // 128 + 8 pad: 2-way-only LDS bank aliasing

typedef unsigned short ushort_t;
typedef unsigned char uchar_t;
typedef unsigned int uint_t;
typedef __attribute__((ext_vector_type(8))) short bf16x8;
typedef __attribute__((ext_vector_type(4))) float f32x4;

__device__ __forceinline__ float bfl(uint_t u) {
    union { uint_t i; float f; } v; v.i = u << 16; return v.f;
}
__device__ __forceinline__ float bfh(uint_t u) {
    union { uint_t i; float f; } v; v.i = u & 0xffff0000u; return v.f;
}
__device__ __forceinline__ ushort_t f2bf(float f) {
    union { float f; uint_t i; } v; v.f = f;
    uint_t x = v.i;
    return (ushort_t)((x + 0x7fffu + ((x >> 16) & 1u)) >> 16);
}
__device__ __forceinline__ uint_t pack2(float lo, float hi) {
    return ((uint_t)f2bf(hi) << 16) | (uint_t)f2bf(lo);
}

// ---------------- front mega-kernel: {sentinel | wprep | dual coarse-hist | zero} ----------------
__global__ void k_front(const int* __restrict__ src, const int* __restrict__ dst,
                        ushort_t* __restrict__ bufA, int* __restrict__ esrc,
                        const float* __restrict__ w1, const float* __restrict__ w2,
                        const float* __restrict__ w3, ushort_t* __restrict__ wbt,
                        int* __restrict__ GG, int* __restrict__ zp, int zwords) {
    __shared__ int hh[NBUCK];
    __shared__ int hh2[NBUCK];
    int b = blockIdx.x;
    int t = threadIdx.x;
    if (b < NB_SENT) {  // esrc sentinel fill + zero bufA sentinel feature row
        int i0 = (b * 256 + t) * 8;
        int4 sv = make_int4(N_NODES, N_NODES, N_NODES, N_NODES);
        if (i0 + 8 <= EPAD) {
            *(int4*)(esrc + i0) = sv;
            *(int4*)(esrc + i0 + 4) = sv;
        } else {
            for (int i = i0; i < EPAD; ++i) esrc[i] = N_NODES;
        }
        if (b == 0 && t < 64)
            ((uint_t*)(bufA + (size_t)N_NODES * DIM))[t] = 0u;
        return;
    }
    b -= NB_SENT;
    if (b < NB_WPREP) {  // W fp32 [k][n] -> bf16 transposed [n][k]
        int i = b * 256 + t;
        int l = i >> 14;
        int idx = i & (DIM * DIM - 1);
        int n = idx >> 7, k = idx & (DIM - 1);
        const float* wsrc = (l == 0) ? w1 : (l == 1) ? w2 : w3;
        wbt[i] = f2bf(wsrc[k * DIM + n]);
        return;
    }
    b -= NB_WPREP;
    if (b < NB_HIST) {  // dual coarse histogram (dst>>7 and src>>7): 4096 edges/chunk
        for (int k = t; k < NBUCK; k += 256) { hh[k] = 0; hh2[k] = 0; }
        __syncthreads();
        int e0 = b * 4096;
        int e1 = min(e0 + 4096, N_EDGES);
        for (int i = e0 + t; i < e1; i += 256) {
            atomicAdd(&hh[dst[i] >> 7], 1);
            atomicAdd(&hh2[src[i] >> 7], 1);
        }
        __syncthreads();
        for (int k = t; k < NBUCK; k += 256) {
            GG[k * NB_HIST + b] = hh[k];
            GG[NG + k * NB_HIST + b] = hh2[k];
        }
        return;
    }
    b -= NB_HIST;
    {  // zero scratch region (bnsum/bnsq/pool/cnt)
        int i = b * 256 + t;
        if (i < zwords) zp[i] = 0;
    }
}

// ---------------- scan of GG (both sides concatenated) -> exclusive Gs ----------------
__global__ void k_scanA(const int* __restrict__ GG, int* __restrict__ Gs,
                        int* __restrict__ partials) {
    __shared__ int s[256];
    int t = threadIdx.x;
    int i = blockIdx.x * 256 + t;
    int v = (i < 2 * NG) ? GG[i] : 0;
    s[t] = v;
    __syncthreads();
    for (int off = 1; off < 256; off <<= 1) {
        int add = (t >= off) ? s[t - off] : 0;
        __syncthreads();
        s[t] += add;
        __syncthreads();
    }
    if (i < 2 * NG) Gs[i + 1] = s[t];
    if (t == 255) partials[blockIdx.x] = s[t];
}

__global__ void k_scanB(const int* __restrict__ partials, int* __restrict__ Gs) {
    __shared__ int s[256];
    int t = threadIdx.x;
    int p = 0;
    for (int j = t; j < (int)blockIdx.x; j += 256) p += partials[j];
    s[t] = p;
    __syncthreads();
    for (int off = 128; off > 0; off >>= 1) {
        if (t < off) s[t] += s[t + off];
        __syncthreads();
    }
    int prefix = s[0];
    int i = blockIdx.x * 256 + t;
    if (i < 2 * NG) Gs[i + 1] += prefix;
    if (blockIdx.x == 0 && t == 0) Gs[0] = 0;
}

// ---------------- pass 2: coarse scatter, dst side (Csrc,Cdl) + src side (Cls) ----------------
__global__ void k_pass2(const int* __restrict__ src, const int* __restrict__ dst,
                        const int* __restrict__ Gs, int* __restrict__ Csrc,
                        uchar_t* __restrict__ Cdl, uchar_t* __restrict__ Cls) {
    __shared__ int cur[NBUCK];
    __shared__ int cur2[NBUCK];
    int b = blockIdx.x;  // 391 blocks
    int t = threadIdx.x;
    for (int k = t; k < NBUCK; k += 256) {
        cur[k] = Gs[k * NB_HIST + b];
        cur2[k] = Gs[NG + k * NB_HIST + b] - N_EDGES;
    }
    __syncthreads();
    int e0 = b * 4096;
    int e1 = min(e0 + 4096, N_EDGES);
    for (int i = e0 + t; i < e1; i += 256) {
        int d = dst[i];
        int s = src[i];
        int slot = atomicAdd(&cur[d >> 7], 1);
        Csrc[slot] = s;
        Cdl[slot] = (uchar_t)(d & 127);
        int slot2 = atomicAdd(&cur2[s >> 7], 1);
        Cls[slot2] = (uchar_t)(s & 127);
    }
}

// ---------------- pass 3, dual partition:
// blocks [0,NBUCK): dst-side fine build (rowptr/pdeg/nd + esrc)
// blocks [NBUCK,2*NBUCK): src-side fine histogram -> ns ----------------
__global__ void k_fine(const int* __restrict__ Csrc, const uchar_t* __restrict__ Cdl,
                       const uchar_t* __restrict__ Cls, const int* __restrict__ Gs,
                       int* __restrict__ esrc, int* __restrict__ rowptr,
                       int* __restrict__ pdeg, float* __restrict__ ns,
                       float* __restrict__ nd) {
    __shared__ int hcnt[128];
    __shared__ int hstart[128];
    int b = blockIdx.x;
    int t = threadIdx.x;
    if (b < NBUCK) {  // dst side
        int k = b;
        int node0 = k * 128;
        int nn = min(128, N_NODES - node0);
        int S = Gs[k * NB_HIST];
        int E = Gs[(k + 1) * NB_HIST];
        if (t < 128) hcnt[t] = 0;
        __syncthreads();
        for (int i = S + t; i < E; i += 256) atomicAdd(&hcnt[Cdl[i]], 1);
        __syncthreads();
        if (t == 0) {
            int acc = 0;
            for (int n = 0; n < nn; ++n) {
                hstart[n] = acc;
                acc += (hcnt[n] + 3) & ~3;
            }
        }
        __syncthreads();
        int base = (k * BUCK_RESERVE + S + 3) & ~3;
        if (t < nn) {
            int node = node0 + t;
            rowptr[node] = base + hstart[t];
            pdeg[node] = (hcnt[t] + 3) & ~3;
            nd[node] = rsqrtf(fmaxf((float)hcnt[t], 1.0f));
        }
        __syncthreads();
        for (int i = S + t; i < E; i += 256) {
            int slot = atomicAdd(&hstart[Cdl[i]], 1);
            esrc[base + slot] = Csrc[i];
        }
    } else {  // src side -> ns
        int k = b - NBUCK;
        int node0 = k * 128;
        int nn = min(128, N_NODES - node0);
        int S = Gs[NG + k * NB_HIST] - N_EDGES;
        int E = Gs[NG + (k + 1) * NB_HIST] - N_EDGES;
        if (t < 128) hcnt[t] = 0;
        __syncthreads();
        for (int i = S + t; i < E; i += 256) atomicAdd(&hcnt[Cls[i]], 1);
        __syncthreads();
        if (t < nn)
            ns[node0 + t] = rsqrtf(fmaxf((float)hcnt[t], 1.0f));
        if (k == 0 && t == 0) ns[N_NODES] = 0.f;  // kills sentinel contributions
    }
}

// ---------------- fused embed gather + l0 prescale: bufA = bf16(embed[token]) * ns ----------------
__global__ void k_embed_ps(const int* __restrict__ tokens, const float* __restrict__ embed,
                           const float* __restrict__ ns, ushort_t* __restrict__ bufA) {
    int gid = blockIdx.x * 256 + threadIdx.x;  // 6250 blocks * 256 = N*16 exactly
    int node = gid >> 4, sub = gid & 15;
    float s = ns[node];
    const float* ep = embed + (size_t)tokens[node] * DIM + sub * 8;
    float4 a = *(const float4*)ep;
    float4 c = *(const float4*)(ep + 4);
    uint4 o;
    o.x = pack2(a.x * s, a.y * s);
    o.y = pack2(a.z * s, a.w * s);
    o.z = pack2(c.x * s, c.y * s);
    o.w = pack2(c.z * s, c.w * s);
    *(uint4*)(bufA + (size_t)node * DIM + sub * 8) = o;
}

// ---------------- prescale: x[v] = relu(fma(y,a,c)) * ns[v], bf16 (BN layers) ----------------
__global__ void k_prescale(const ushort_t* __restrict__ yin, const float* __restrict__ ns,
                           const float* __restrict__ bnsum, const float* __restrict__ bnsq,
                           const float* __restrict__ g, const float* __restrict__ be,
                           ushort_t* __restrict__ xout) {
    __shared__ float sa[DIM], sc[DIM];
    int t = threadIdx.x;
    if (t < DIM) {
        float mu = bnsum[t] * (1.0f / N_NODES);
        float var = bnsq[t] * (1.0f / N_NODES) - mu * mu;
        float rstd = rsqrtf(var + BN_EPS);
        float a = g[t] * rstd;
        sa[t] = a;
        sc[t] = be[t] - mu * a;
    }
    __syncthreads();
    int gid = blockIdx.x * 256 + t;  // 6250 blocks * 256 = N*16 exactly
    int node = gid >> 4, sub = gid & 15;
    float s = ns[node];
    uint4 u = *(const uint4*)(yin + (size_t)node * DIM + sub * 8);
    float v[8] = {bfl(u.x), bfh(u.x), bfl(u.y), bfh(u.y),
                  bfl(u.z), bfh(u.z), bfl(u.w), bfh(u.w)};
    const float* a = sa + sub * 8;
    const float* c = sc + sub * 8;
#pragma unroll
    for (int i = 0; i < 8; ++i) v[i] = fmaxf(fmaf(v[i], a[i], c[i]), 0.f) * s;
    uint4 o;
    o.x = pack2(v[0], v[1]); o.y = pack2(v[2], v[3]);
    o.z = pack2(v[4], v[5]); o.w = pack2(v[6], v[7]);
    *(uint4*)(xout + (size_t)node * DIM + sub * 8) = o;
}

// ---------------- FUSED pure-sum gather (2-node pipeline, idx prefetched one
// iteration ahead) -> LDS -> MFMA + BN stats. 256-thread blocks, 64 nodes.
// Block-shared stats (LDS atomics) shrink LDS to 18.4 KB -> 8 blocks/CU.
// No barrier between gather and MFMA (A-tile rows are wave-private). ----------------
__global__ __launch_bounds__(256) void k_agggemm(const ushort_t* __restrict__ hs,
        const int* __restrict__ rowptr, const int* __restrict__ pdeg,
        const int* __restrict__ esrc, const float* __restrict__ nd,
        const ushort_t* __restrict__ wbt, const float* __restrict__ bias,
        ushort_t* __restrict__ y,
        float* __restrict__ bnsum, float* __restrict__ bnsq) {
    __shared__ ushort_t at[64 * AT_STRIDE];
    __shared__ float csum[DIM], csq[DIM];
    int tid = threadIdx.x;
    int wave = tid >> 6;
    int lane = tid & 63;
    if (tid < DIM) { csum[tid] = 0.f; csq[tid] = 0.f; }
    __syncthreads();  // startup-only barrier (waves are ~aligned here; cheap)

    int bnode = blockIdx.x * 64 + wave * 16;
    int off = lane * 2;

    // prefetch the wave's 16 row starts + padded degrees, serve via shfl
    int rpv = 0, pdv = 0;
    if (lane < 16) {
        int nnode = bnode + lane;
        if (nnode < N_NODES) { rpv = rowptr[nnode]; pdv = pdeg[nnode]; }
    }

#define LD2(s) (*(const uint_t*)(hs + (size_t)(s) * DIM + off))
#define ACC8(I0, I1, X0, Y0, X1, Y1)                                           \
    {                                                                          \
        uint_t u0 = LD2(I0.x), u1 = LD2(I0.y), u2 = LD2(I0.z), u3 = LD2(I0.w); \
        uint_t u4 = LD2(I1.x), u5 = LD2(I1.y), u6 = LD2(I1.z), u7 = LD2(I1.w); \
        X0 += bfl(u0); Y0 += bfh(u0); X1 += bfl(u1); Y1 += bfh(u1);            \
        X0 += bfl(u2); Y0 += bfh(u2); X1 += bfl(u3); Y1 += bfh(u3);            \
        X0 += bfl(u4); Y0 += bfh(u4); X1 += bfl(u5); Y1 += bfh(u5);            \
        X0 += bfl(u6); Y0 += bfh(u6); X1 += bfl(u7); Y1 += bfh(u7);            \
    }
#define ACC4(I0, X0, Y0, X1, Y1)                                               \
    {                                                                          \
        uint_t u0 = LD2(I0.x), u1 = LD2(I0.y), u2 = LD2(I0.z), u3 = LD2(I0.w); \
        X0 += bfl(u0); Y0 += bfh(u0); X1 += bfl(u1); Y1 += bfh(u1);            \
        X0 += bfl(u2); Y0 += bfh(u2); X1 += bfl(u3); Y1 += bfh(u3);            \
    }

    // ---- phase 1: gather, 2 nodes in flight, indices pipelined 1 iter ahead ----
    for (int i = 0; i < 16; i += 2) {
        int nodeA = bnode + i;
        int nodeB = bnode + i + 1;
        int eA = __shfl(rpv, i);
        int endA = eA + __shfl(pdv, i);
        int eB = __shfl(rpv, i + 1);
        int endB = eB + __shfl(pdv, i + 1);
        float xA0 = 0.f, yA0 = 0.f, xA1 = 0.f, yA1 = 0.f;
        float xB0 = 0.f, yB0 = 0.f, xB1 = 0.f, yB1 = 0.f;
        // joint main loop: 16 feature loads in flight; next iter's idx loads
        // issued under the feature-load latency (prefetch past row end is safe:
        // EPAD slack; values discarded on exit).
        if (eA + 8 <= endA && eB + 8 <= endB) {
            int4 cA0 = *(const int4*)(esrc + eA);
            int4 cA1 = *(const int4*)(esrc + eA + 4);
            int4 cB0 = *(const int4*)(esrc + eB);
            int4 cB1 = *(const int4*)(esrc + eB + 4);
            while (true) {
                int4 nA0 = *(const int4*)(esrc + eA + 8);
                int4 nA1 = *(const int4*)(esrc + eA + 12);
                int4 nB0 = *(const int4*)(esrc + eB + 8);
                int4 nB1 = *(const int4*)(esrc + eB + 12);
                ACC8(cA0, cA1, xA0, yA0, xA1, yA1);
                ACC8(cB0, cB1, xB0, yB0, xB1, yB1);
                eA += 8; eB += 8;
                if (!(eA + 8 <= endA && eB + 8 <= endB)) break;
                cA0 = nA0; cA1 = nA1; cB0 = nB0; cB1 = nB1;
            }
        }
        // drain A
        for (; eA + 8 <= endA; eA += 8) {
            int4 i0 = *(const int4*)(esrc + eA);
            int4 i1 = *(const int4*)(esrc + eA + 4);
            ACC8(i0, i1, xA0, yA0, xA1, yA1);
        }
        if (eA < endA) {  // exactly 4 (rows padded to x4)
            int4 i0 = *(const int4*)(esrc + eA);
            ACC4(i0, xA0, yA0, xA1, yA1);
        }
        // drain B
        for (; eB + 8 <= endB; eB += 8) {
            int4 i0 = *(const int4*)(esrc + eB);
            int4 i1 = *(const int4*)(esrc + eB + 4);
            ACC8(i0, i1, xB0, yB0, xB1, yB1);
        }
        if (eB < endB) {
            int4 i0 = *(const int4*)(esrc + eB);
            ACC4(i0, xB0, yB0, xB1, yB1);
        }
        // finalize both nodes
        uint_t ovA = 0u, ovB = 0u;
        if (nodeA < N_NODES) {
            float n = nd[nodeA];
            ovA = pack2((xA0 + xA1) * n, (yA0 + yA1) * n);
        }
        if (nodeB < N_NODES) {
            float n = nd[nodeB];
            ovB = pack2((xB0 + xB1) * n, (yB0 + yB1) * n);
        }
        *(uint_t*)&at[(wave * 16 + i) * AT_STRIDE + off] = ovA;
        *(uint_t*)&at[(wave * 16 + i + 1) * AT_STRIDE + off] = ovB;
    }
#undef ACC8
#undef ACC4
#undef LD2
    // NO barrier: each wave's MFMA reads only its own 16 LDS rows.

    // ---- phase 2: MFMA (D: col=lane&15, row=quad*4+reg) ----
    int m16 = lane & 15;
    int quad = lane >> 4;
    f32x4 acc[8];
#pragma unroll
    for (int nb = 0; nb < 8; ++nb) acc[nb] = (f32x4)(0.f);

    const ushort_t* ap = &at[(wave * 16 + m16) * AT_STRIDE + quad * 8];
#pragma unroll
    for (int k0b = 0; k0b < 4; ++k0b) {
        bf16x8 af = *(const bf16x8*)(ap + k0b * 32);
#pragma unroll
        for (int nb = 0; nb < 8; ++nb) {
            int ncol = nb * 16 + m16;
            bf16x8 bfg = *(const bf16x8*)(wbt + (size_t)ncol * DIM + k0b * 32 + quad * 8);
            acc[nb] = __builtin_amdgcn_mfma_f32_16x16x32_bf16(af, bfg, acc[nb], 0, 0, 0);
        }
    }

    // epilogue: bias, block-shared BN partial stats (LDS atomics), bf16 store
#pragma unroll
    for (int nb = 0; nb < 8; ++nb) {
        int col = nb * 16 + m16;
        float bcol = bias[col];
        float ps = 0.f, pq = 0.f;
#pragma unroll
        for (int reg = 0; reg < 4; ++reg) {
            int r = bnode + quad * 4 + reg;
            if (r < N_NODES) {
                float v = acc[nb][reg] + bcol;
                ps += v; pq += v * v;
                y[(size_t)r * DIM + col] = f2bf(v);
            }
        }
        atomicAdd(&csum[col], ps);
        atomicAdd(&csq[col], pq);
    }
    __syncthreads();  // final barrier: stats complete before global reduce
    if (tid < DIM) {
        atomicAdd(&bnsum[tid], csum[tid]);
        atomicAdd(&bnsq[tid], csq[tid]);
    }
}

// ---------------- pooling: fused layer-3 BN fold+apply + graph counts ----------------
#define POOL_NODES 128
__global__ void k_pool(const ushort_t* __restrict__ yin, const int* __restrict__ gids,
                       const float* __restrict__ bnsum, const float* __restrict__ bnsq,
                       const float* __restrict__ g, const float* __restrict__ be,
                       float* __restrict__ pool, int* __restrict__ cnt) {
    __shared__ int h[N_GRAPHS];
    int col = threadIdx.x;  // 128
    float mu = bnsum[col] * (1.0f / N_NODES);
    float var = bnsq[col] * (1.0f / N_NODES) - mu * mu;
    float rstd = rsqrtf(var + BN_EPS);
    float a = g[col] * rstd;
    float c = be[col] - mu * a;
    if (col < N_GRAPHS) h[col] = 0;
    __syncthreads();
    int base = blockIdx.x * POOL_NODES;
    int end = min(base + POOL_NODES, N_NODES);
    for (int n = base + col; n < end; n += 128) atomicAdd(&h[gids[n]], 1);
    __syncthreads();
    if (col < N_GRAPHS && h[col]) atomicAdd(&cnt[col], h[col]);
    float acc = 0.f;
    int cur = gids[base];
    for (int n = base; n < end; ++n) {
        int gg = gids[n];
        if (gg != cur) {
            atomicAdd(&pool[(size_t)cur * DIM + col], acc);
            acc = 0.f;
            cur = gg;
        }
        uint_t u = *(const uint_t*)(yin + (size_t)n * DIM + (col & ~1));
        float v = (col & 1) ? bfh(u) : bfl(u);
        acc += fmaxf(fmaf(v, a, c), 0.f);
    }
    atomicAdd(&pool[(size_t)cur * DIM + col], acc);
}

// ---------------- final FC (one block per graph) ----------------
__global__ void k_final(const float* __restrict__ pool, const int* __restrict__ cnt,
                        const float* __restrict__ fcW1, const float* __restrict__ fcb1,
                        const float* __restrict__ fcW2, const float* __restrict__ fcb2,
                        float* __restrict__ out) {
    __shared__ float hg[DIM];
    __shared__ float z[64];
    int g = blockIdx.x;
    int t = threadIdx.x;  // 128
    float cf = fmaxf((float)cnt[g], 1.0f);
    hg[t] = pool[(size_t)g * DIM + t] / cf;
    __syncthreads();
    if (t < 64) {
        float acc = fcb1[t];
        for (int k = 0; k < DIM; ++k)
            acc += hg[k] * fcW1[k * 64 + t];
        z[t] = fmaxf(acc, 0.f);
    }
    __syncthreads();
    if (t < 2) {
        float acc = fcb2[t];
        for (int k = 0; k < 64; ++k)
            acc += z[k] * fcW2[k * 2 + t];
        out[g * 2 + t] = acc;
    }
}

extern "C" void kernel_launch(void* const* d_in, const int* in_sizes, int n_in,
                              void* d_out, int out_size, void* d_ws, size_t ws_size,
                              hipStream_t stream) {
    const int* tokens = (const int*)d_in[0];
    const int* src = (const int*)d_in[1];
    const int* dst = (const int*)d_in[2];
    const int* gids = (const int*)d_in[3];
    const float* embed = (const float*)d_in[4];
    const float* W1 = (const float*)d_in[5];
    const float* b1 = (const float*)d_in[6];
    const float* g1 = (const float*)d_in[7];
    const float* be1 = (const float*)d_in[8];
    const float* W2 = (const float*)d_in[9];
    const float* b2 = (const float*)d_in[10];
    const float* g2 = (const float*)d_in[11];
    const float* be2 = (const float*)d_in[12];
    const float* W3 = (const float*)d_in[13];
    const float* b3 = (const float*)d_in[14];
    const float* g3 = (const float*)d_in[15];
    const float* be3 = (const float*)d_in[16];
    const float* fcW1 = (const float*)d_in[17];
    const float* fcb1 = (const float*)d_in[18];
    const float* fcW2 = (const float*)d_in[19];
    const float* fcb2 = (const float*)d_in[20];
    float* out = (float*)d_out;

    char* w = (char*)d_ws;
    auto alloc = [&](size_t bytes) {
        void* p = (void*)w;
        w += (bytes + 255) & ~(size_t)255;
        return p;
    };
    ushort_t* bufH = (ushort_t*)alloc((size_t)(N_NODES + 1) * DIM * 2);  // y2
    ushort_t* bufA = (ushort_t*)alloc((size_t)(N_NODES + 1) * DIM * 2);  // prescaled gather input
    ushort_t* bufY = (ushort_t*)alloc((size_t)(N_NODES + 1) * DIM * 2);  // y1 / y3
    int* esrc = (int*)alloc((size_t)EPAD * 4);
    int* rowptr = (int*)alloc((size_t)N_NODES * 4);
    int* pdeg = (int*)alloc((size_t)N_NODES * 4);
    float* ns = (float*)alloc((size_t)(N_NODES + 1) * 4);
    float* nd = (float*)alloc((size_t)N_NODES * 4);
    ushort_t* wbt = (ushort_t*)alloc(3 * DIM * DIM * 2);
    int* GG = (int*)alloc((size_t)(2 * NG) * 4);
    int* Gs = (int*)alloc((size_t)(2 * NG + 1) * 4);
    int* partials = (int*)alloc(4096 * 4);
    int* Csrc = (int*)alloc((size_t)N_EDGES * 4);
    uchar_t* Cdl = (uchar_t*)alloc((size_t)N_EDGES);
    uchar_t* Cls = (uchar_t*)alloc((size_t)N_EDGES);
    // zeroed region (contiguous)
    char* zstart = w;
    float* bnsum = (float*)alloc(3 * DIM * 4);
    float* bnsq = (float*)alloc(3 * DIM * 4);
    float* pool = (float*)alloc((size_t)N_GRAPHS * DIM * 4);
    int* cnt = (int*)alloc((size_t)N_GRAPHS * 4);
    int zwords = (int)((size_t)(w - zstart) / 4);

    k_front<<<NB_SENT + NB_WPREP + NB_HIST + NB_ZERO, 256, 0, stream>>>(
        src, dst, bufA, esrc, W1, W2, W3, wbt, GG, (int*)zstart, zwords);
    k_scanA<<<NB_SCANG2, 256, 0, stream>>>(GG, Gs, partials);
    k_scanB<<<NB_SCANG2, 256, 0, stream>>>(partials, Gs);
    k_pass2<<<NB_HIST, 256, 0, stream>>>(src, dst, Gs, Csrc, Cdl, Cls);
    k_fine<<<2 * NBUCK, 256, 0, stream>>>(Csrc, Cdl, Cls, Gs, esrc, rowptr, pdeg, ns, nd);

    int nb_fused = (N_NODES + 63) / 64;  // 256-thread blocks, 64 nodes each
    int nb_ps = 6250;                    // N*16/256

    // l=0: fused embed+prescale -> bufA; gather bufA -> y1 in bufY
    k_embed_ps<<<nb_ps, 256, 0, stream>>>(tokens, embed, ns, bufA);
    k_agggemm<<<nb_fused, 256, 0, stream>>>(bufA, rowptr, pdeg, esrc, nd,
                                            wbt, b1, bufY, bnsum, bnsq);
    // l=1: prescale bufY (BN stats1) -> bufA; gather -> y2 in bufH
    k_prescale<<<nb_ps, 256, 0, stream>>>(bufY, ns, bnsum, bnsq, g1, be1, bufA);
    k_agggemm<<<nb_fused, 256, 0, stream>>>(bufA, rowptr, pdeg, esrc, nd,
                                            wbt + (size_t)DIM * DIM, b2, bufH,
                                            bnsum + DIM, bnsq + DIM);
    // l=2: prescale bufH (BN stats2) -> bufA; gather -> y3 in bufY
    k_prescale<<<nb_ps, 256, 0, stream>>>(bufH, ns, bnsum + DIM, bnsq + DIM, g2, be2, bufA);
    k_agggemm<<<nb_fused, 256, 0, stream>>>(bufA, rowptr, pdeg, esrc, nd,
                                            wbt + (size_t)2 * DIM * DIM, b3, bufY,
                                            bnsum + 2 * DIM, bnsq + 2 * DIM);

    k_pool<<<(N_NODES + POOL_NODES - 1) / POOL_NODES, DIM, 0, stream>>>(
        bufY, gids, bnsum + 2 * DIM, bnsq + 2 * DIM, g3, be3, pool, cnt);
    k_final<<<N_GRAPHS, DIM, 0, stream>>>(pool, cnt, fcW1, fcb1, fcW2, fcb2, out);
}

// Round 23
// 633.680 us; speedup vs baseline: 1.1759x; 1.0346x over previous
//
#include <hip/hip_runtime.h>

#define N_NODES 100000
#define N_EDGES 1600000
#define N_GRAPHS 64
#define DIM 128
#define BN_EPS 1e-5f
#define EPAD 2000000          // sentinel-filled esrc capacity (needs 1,903,419)

#define NB_SENT 977           // esrc sentinel fill, 8 per thread
#define NB_WPREP 192          // 3*128*128/256
#define NB_HIST 391           // coarse hist: 391 chunks * 4096 edges
#define NB_ZERO 40            // zero scratch: 40*256 = 10240 words >= zwords
#define NBUCK 782             // coarse buckets = id>>7 (100000/128)
#define NG (NBUCK * NB_HIST)  // per-side count-matrix size = 305762
#define NB_SCANG2 2389        // ceil(2*NG/256)
#define BUCK_RESERVE 388      // cnt + 128*3 pad + 4 align slack

#define AT_STRIDE 136  // 128 + 8 pad: 2-way-only LDS bank aliasing

typedef unsigned short ushort_t;
typedef unsigned char uchar_t;
typedef unsigned int uint_t;
typedef __attribute__((ext_vector_type(8))) short bf16x8;
typedef __attribute__((ext_vector_type(4))) float f32x4;

__device__ __forceinline__ float bfl(uint_t u) {
    union { uint_t i; float f; } v; v.i = u << 16; return v.f;
}
__device__ __forceinline__ float bfh(uint_t u) {
    union { uint_t i; float f; } v; v.i = u & 0xffff0000u; return v.f;
}
__device__ __forceinline__ ushort_t f2bf(float f) {
    union { float f; uint_t i; } v; v.f = f;
    uint_t x = v.i;
    return (ushort_t)((x + 0x7fffu + ((x >> 16) & 1u)) >> 16);
}
__device__ __forceinline__ uint_t pack2(float lo, float hi) {
    return ((uint_t)f2bf(hi) << 16) | (uint_t)f2bf(lo);
}

// ---------------- front mega-kernel: {sentinel | wprep | dual coarse-hist | zero} ----------------
__global__ void k_front(const int* __restrict__ src, const int* __restrict__ dst,
                        ushort_t* __restrict__ bufA, int* __restrict__ esrc,
                        const float* __restrict__ w1, const float* __restrict__ w2,
                        const float* __restrict__ w3, ushort_t* __restrict__ wbt,
                        int* __restrict__ GG, int* __restrict__ zp, int zwords) {
    __shared__ int hh[NBUCK];
    __shared__ int hh2[NBUCK];
    int b = blockIdx.x;
    int t = threadIdx.x;
    if (b < NB_SENT) {  // esrc sentinel fill + zero bufA sentinel feature row
        int i0 = (b * 256 + t) * 8;
        int4 sv = make_int4(N_NODES, N_NODES, N_NODES, N_NODES);
        if (i0 + 8 <= EPAD) {
            *(int4*)(esrc + i0) = sv;
            *(int4*)(esrc + i0 + 4) = sv;
        } else {
            for (int i = i0; i < EPAD; ++i) esrc[i] = N_NODES;
        }
        if (b == 0 && t < 64)
            ((uint_t*)(bufA + (size_t)N_NODES * DIM))[t] = 0u;
        return;
    }
    b -= NB_SENT;
    if (b < NB_WPREP) {  // W fp32 [k][n] -> bf16 transposed [n][k]
        int i = b * 256 + t;
        int l = i >> 14;
        int idx = i & (DIM * DIM - 1);
        int n = idx >> 7, k = idx & (DIM - 1);
        const float* wsrc = (l == 0) ? w1 : (l == 1) ? w2 : w3;
        wbt[i] = f2bf(wsrc[k * DIM + n]);
        return;
    }
    b -= NB_WPREP;
    if (b < NB_HIST) {  // dual coarse histogram (dst>>7 and src>>7): 4096 edges/chunk
        for (int k = t; k < NBUCK; k += 256) { hh[k] = 0; hh2[k] = 0; }
        __syncthreads();
        int e0 = b * 4096;
        int e1 = min(e0 + 4096, N_EDGES);
        for (int i = e0 + t; i < e1; i += 256) {
            atomicAdd(&hh[dst[i] >> 7], 1);
            atomicAdd(&hh2[src[i] >> 7], 1);
        }
        __syncthreads();
        for (int k = t; k < NBUCK; k += 256) {
            GG[k * NB_HIST + b] = hh[k];
            GG[NG + k * NB_HIST + b] = hh2[k];
        }
        return;
    }
    b -= NB_HIST;
    {  // zero scratch region (bnsum/bnsq/pool/cnt)
        int i = b * 256 + t;
        if (i < zwords) zp[i] = 0;
    }
}

// ---------------- scan of GG (both sides concatenated) -> exclusive Gs ----------------
__global__ void k_scanA(const int* __restrict__ GG, int* __restrict__ Gs,
                        int* __restrict__ partials) {
    __shared__ int s[256];
    int t = threadIdx.x;
    int i = blockIdx.x * 256 + t;
    int v = (i < 2 * NG) ? GG[i] : 0;
    s[t] = v;
    __syncthreads();
    for (int off = 1; off < 256; off <<= 1) {
        int add = (t >= off) ? s[t - off] : 0;
        __syncthreads();
        s[t] += add;
        __syncthreads();
    }
    if (i < 2 * NG) Gs[i + 1] = s[t];
    if (t == 255) partials[blockIdx.x] = s[t];
}

__global__ void k_scanB(const int* __restrict__ partials, int* __restrict__ Gs) {
    __shared__ int s[256];
    int t = threadIdx.x;
    int p = 0;
    for (int j = t; j < (int)blockIdx.x; j += 256) p += partials[j];
    s[t] = p;
    __syncthreads();
    for (int off = 128; off > 0; off >>= 1) {
        if (t < off) s[t] += s[t + off];
        __syncthreads();
    }
    int prefix = s[0];
    int i = blockIdx.x * 256 + t;
    if (i < 2 * NG) Gs[i + 1] += prefix;
    if (blockIdx.x == 0 && t == 0) Gs[0] = 0;
}

// ---------------- pass 2: coarse scatter. dst side: packed (src | dl<<17) uint;
// src side: fine-bin bytes (Cls). ----------------
__global__ void k_pass2(const int* __restrict__ src, const int* __restrict__ dst,
                        const int* __restrict__ Gs, uint_t* __restrict__ Cpk,
                        uchar_t* __restrict__ Cls) {
    __shared__ int cur[NBUCK];
    __shared__ int cur2[NBUCK];
    int b = blockIdx.x;  // 391 blocks
    int t = threadIdx.x;
    for (int k = t; k < NBUCK; k += 256) {
        cur[k] = Gs[k * NB_HIST + b];
        cur2[k] = Gs[NG + k * NB_HIST + b] - N_EDGES;
    }
    __syncthreads();
    int e0 = b * 4096;
    int e1 = min(e0 + 4096, N_EDGES);
    for (int i = e0 + t; i < e1; i += 256) {
        int d = dst[i];
        int s = src[i];
        int slot = atomicAdd(&cur[d >> 7], 1);
        Cpk[slot] = (uint_t)s | ((uint_t)(d & 127) << 17);
        int slot2 = atomicAdd(&cur2[s >> 7], 1);
        Cls[slot2] = (uchar_t)(s & 127);
    }
}

// ---------------- pass 3, dual partition:
// blocks [0,NBUCK): dst-side fine build (rowptr/pdeg/nd + esrc)
// blocks [NBUCK,2*NBUCK): src-side fine histogram -> ns, then fused embed+prescale ----------------
__global__ void k_fine(const uint_t* __restrict__ Cpk, const uchar_t* __restrict__ Cls,
                       const int* __restrict__ Gs,
                       const int* __restrict__ tokens, const float* __restrict__ embed,
                       int* __restrict__ esrc, int* __restrict__ rowptr,
                       int* __restrict__ pdeg, float* __restrict__ ns,
                       float* __restrict__ nd, ushort_t* __restrict__ bufA) {
    __shared__ int hcnt[128];
    __shared__ int hstart[128];
    __shared__ float lns[128];
    int b = blockIdx.x;
    int t = threadIdx.x;
    if (b < NBUCK) {  // dst side
        int k = b;
        int node0 = k * 128;
        int nn = min(128, N_NODES - node0);
        int S = Gs[k * NB_HIST];
        int E = Gs[(k + 1) * NB_HIST];
        if (t < 128) hcnt[t] = 0;
        __syncthreads();
        for (int i = S + t; i < E; i += 256) atomicAdd(&hcnt[Cpk[i] >> 17], 1);
        __syncthreads();
        if (t == 0) {
            int acc = 0;
            for (int n = 0; n < nn; ++n) {
                hstart[n] = acc;
                acc += (hcnt[n] + 3) & ~3;
            }
        }
        __syncthreads();
        int base = (k * BUCK_RESERVE + S + 3) & ~3;
        if (t < nn) {
            int node = node0 + t;
            rowptr[node] = base + hstart[t];
            pdeg[node] = (hcnt[t] + 3) & ~3;
            nd[node] = rsqrtf(fmaxf((float)hcnt[t], 1.0f));
        }
        __syncthreads();
        for (int i = S + t; i < E; i += 256) {
            uint_t pk = Cpk[i];
            int slot = atomicAdd(&hstart[pk >> 17], 1);
            esrc[base + slot] = (int)(pk & 0x1FFFFu);
        }
    } else {  // src side -> ns, then fused embed gather + l0 prescale
        int k = b - NBUCK;
        int node0 = k * 128;
        int nn = min(128, N_NODES - node0);
        int S = Gs[NG + k * NB_HIST] - N_EDGES;
        int E = Gs[NG + (k + 1) * NB_HIST] - N_EDGES;
        if (t < 128) hcnt[t] = 0;
        __syncthreads();
        for (int i = S + t; i < E; i += 256) atomicAdd(&hcnt[Cls[i]], 1);
        __syncthreads();
        if (t < nn) {
            float v = rsqrtf(fmaxf((float)hcnt[t], 1.0f));
            ns[node0 + t] = v;
            lns[t] = v;
        }
        if (k == 0 && t == 0) ns[N_NODES] = 0.f;  // kills sentinel contributions
        __syncthreads();
        // fused embed + l0 prescale for this block's nodes
        for (int slot = t; slot < nn * 16; slot += 256) {
            int nloc = slot >> 4, sub = slot & 15;
            int node = node0 + nloc;
            float s = lns[nloc];
            const float* ep = embed + (size_t)tokens[node] * DIM + sub * 8;
            float4 a = *(const float4*)ep;
            float4 c = *(const float4*)(ep + 4);
            uint4 o;
            o.x = pack2(a.x * s, a.y * s);
            o.y = pack2(a.z * s, a.w * s);
            o.z = pack2(c.x * s, c.y * s);
            o.w = pack2(c.z * s, c.w * s);
            *(uint4*)(bufA + (size_t)node * DIM + sub * 8) = o;
        }
    }
}

// ---------------- prescale: x[v] = relu(fma(y,a,c)) * ns[v], bf16 (BN layers) ----------------
__global__ void k_prescale(const ushort_t* __restrict__ yin, const float* __restrict__ ns,
                           const float* __restrict__ bnsum, const float* __restrict__ bnsq,
                           const float* __restrict__ g, const float* __restrict__ be,
                           ushort_t* __restrict__ xout) {
    __shared__ float sa[DIM], sc[DIM];
    int t = threadIdx.x;
    if (t < DIM) {
        float mu = bnsum[t] * (1.0f / N_NODES);
        float var = bnsq[t] * (1.0f / N_NODES) - mu * mu;
        float rstd = rsqrtf(var + BN_EPS);
        float a = g[t] * rstd;
        sa[t] = a;
        sc[t] = be[t] - mu * a;
    }
    __syncthreads();
    int gid = blockIdx.x * 256 + t;  // 6250 blocks * 256 = N*16 exactly
    int node = gid >> 4, sub = gid & 15;
    float s = ns[node];
    uint4 u = *(const uint4*)(yin + (size_t)node * DIM + sub * 8);
    float v[8] = {bfl(u.x), bfh(u.x), bfl(u.y), bfh(u.y),
                  bfl(u.z), bfh(u.z), bfl(u.w), bfh(u.w)};
    const float* a = sa + sub * 8;
    const float* c = sc + sub * 8;
#pragma unroll
    for (int i = 0; i < 8; ++i) v[i] = fmaxf(fmaf(v[i], a[i], c[i]), 0.f) * s;
    uint4 o;
    o.x = pack2(v[0], v[1]); o.y = pack2(v[2], v[3]);
    o.z = pack2(v[4], v[5]); o.w = pack2(v[6], v[7]);
    *(uint4*)(xout + (size_t)node * DIM + sub * 8) = o;
}

// ---------------- FUSED pure-sum gather (2-node pipeline, idx prefetched one
// iteration ahead) -> LDS -> MFMA + BN stats. 256-thread blocks, 64 nodes.
// Block-shared stats (LDS atomics), 18.4 KB LDS. No barrier between gather
// and MFMA (A-tile rows are wave-private). ----------------
__global__ __launch_bounds__(256) void k_agggemm(const ushort_t* __restrict__ hs,
        const int* __restrict__ rowptr, const int* __restrict__ pdeg,
        const int* __restrict__ esrc, const float* __restrict__ nd,
        const ushort_t* __restrict__ wbt, const float* __restrict__ bias,
        ushort_t* __restrict__ y,
        float* __restrict__ bnsum, float* __restrict__ bnsq) {
    __shared__ ushort_t at[64 * AT_STRIDE];
    __shared__ float csum[DIM], csq[DIM];
    int tid = threadIdx.x;
    int wave = tid >> 6;
    int lane = tid & 63;
    if (tid < DIM) { csum[tid] = 0.f; csq[tid] = 0.f; }
    __syncthreads();  // startup-only barrier (waves are ~aligned here; cheap)

    int bnode = blockIdx.x * 64 + wave * 16;
    int off = lane * 2;

    // prefetch the wave's 16 row starts + padded degrees, serve via shfl
    int rpv = 0, pdv = 0;
    if (lane < 16) {
        int nnode = bnode + lane;
        if (nnode < N_NODES) { rpv = rowptr[nnode]; pdv = pdeg[nnode]; }
    }

#define LD2(s) (*(const uint_t*)(hs + (size_t)(s) * DIM + off))
#define ACC8(I0, I1, X0, Y0, X1, Y1)                                           \
    {                                                                          \
        uint_t u0 = LD2(I0.x), u1 = LD2(I0.y), u2 = LD2(I0.z), u3 = LD2(I0.w); \
        uint_t u4 = LD2(I1.x), u5 = LD2(I1.y), u6 = LD2(I1.z), u7 = LD2(I1.w); \
        X0 += bfl(u0); Y0 += bfh(u0); X1 += bfl(u1); Y1 += bfh(u1);            \
        X0 += bfl(u2); Y0 += bfh(u2); X1 += bfl(u3); Y1 += bfh(u3);            \
        X0 += bfl(u4); Y0 += bfh(u4); X1 += bfl(u5); Y1 += bfh(u5);            \
        X0 += bfl(u6); Y0 += bfh(u6); X1 += bfl(u7); Y1 += bfh(u7);            \
    }
#define ACC4(I0, X0, Y0, X1, Y1)                                               \
    {                                                                          \
        uint_t u0 = LD2(I0.x), u1 = LD2(I0.y), u2 = LD2(I0.z), u3 = LD2(I0.w); \
        X0 += bfl(u0); Y0 += bfh(u0); X1 += bfl(u1); Y1 += bfh(u1);            \
        X0 += bfl(u2); Y0 += bfh(u2); X1 += bfl(u3); Y1 += bfh(u3);            \
    }

    // ---- phase 1: gather, 2 nodes in flight, indices pipelined 1 iter ahead ----
    for (int i = 0; i < 16; i += 2) {
        int nodeA = bnode + i;
        int nodeB = bnode + i + 1;
        int eA = __shfl(rpv, i);
        int endA = eA + __shfl(pdv, i);
        int eB = __shfl(rpv, i + 1);
        int endB = eB + __shfl(pdv, i + 1);
        float xA0 = 0.f, yA0 = 0.f, xA1 = 0.f, yA1 = 0.f;
        float xB0 = 0.f, yB0 = 0.f, xB1 = 0.f, yB1 = 0.f;
        // joint main loop: 16 feature loads in flight; next iter's idx loads
        // issued under the feature-load latency (prefetch past row end is safe:
        // EPAD slack; values discarded on exit).
        if (eA + 8 <= endA && eB + 8 <= endB) {
            int4 cA0 = *(const int4*)(esrc + eA);
            int4 cA1 = *(const int4*)(esrc + eA + 4);
            int4 cB0 = *(const int4*)(esrc + eB);
            int4 cB1 = *(const int4*)(esrc + eB + 4);
            while (true) {
                int4 nA0 = *(const int4*)(esrc + eA + 8);
                int4 nA1 = *(const int4*)(esrc + eA + 12);
                int4 nB0 = *(const int4*)(esrc + eB + 8);
                int4 nB1 = *(const int4*)(esrc + eB + 12);
                ACC8(cA0, cA1, xA0, yA0, xA1, yA1);
                ACC8(cB0, cB1, xB0, yB0, xB1, yB1);
                eA += 8; eB += 8;
                if (!(eA + 8 <= endA && eB + 8 <= endB)) break;
                cA0 = nA0; cA1 = nA1; cB0 = nB0; cB1 = nB1;
            }
        }
        // drain A
        for (; eA + 8 <= endA; eA += 8) {
            int4 i0 = *(const int4*)(esrc + eA);
            int4 i1 = *(const int4*)(esrc + eA + 4);
            ACC8(i0, i1, xA0, yA0, xA1, yA1);
        }
        if (eA < endA) {  // exactly 4 (rows padded to x4)
            int4 i0 = *(const int4*)(esrc + eA);
            ACC4(i0, xA0, yA0, xA1, yA1);
        }
        // drain B
        for (; eB + 8 <= endB; eB += 8) {
            int4 i0 = *(const int4*)(esrc + eB);
            int4 i1 = *(const int4*)(esrc + eB + 4);
            ACC8(i0, i1, xB0, yB0, xB1, yB1);
        }
        if (eB < endB) {
            int4 i0 = *(const int4*)(esrc + eB);
            ACC4(i0, xB0, yB0, xB1, yB1);
        }
        // finalize both nodes
        uint_t ovA = 0u, ovB = 0u;
        if (nodeA < N_NODES) {
            float n = nd[nodeA];
            ovA = pack2((xA0 + xA1) * n, (yA0 + yA1) * n);
        }
        if (nodeB < N_NODES) {
            float n = nd[nodeB];
            ovB = pack2((xB0 + xB1) * n, (yB0 + yB1) * n);
        }
        *(uint_t*)&at[(wave * 16 + i) * AT_STRIDE + off] = ovA;
        *(uint_t*)&at[(wave * 16 + i + 1) * AT_STRIDE + off] = ovB;
    }
#undef ACC8
#undef ACC4
#undef LD2
    // NO barrier: each wave's MFMA reads only its own 16 LDS rows.

    // ---- phase 2: MFMA (D: col=lane&15, row=quad*4+reg) ----
    int m16 = lane & 15;
    int quad = lane >> 4;
    f32x4 acc[8];
#pragma unroll
    for (int nb = 0; nb < 8; ++nb) acc[nb] = (f32x4)(0.f);

    const ushort_t* ap = &at[(wave * 16 + m16) * AT_STRIDE + quad * 8];
#pragma unroll
    for (int k0b = 0; k0b < 4; ++k0b) {
        bf16x8 af = *(const bf16x8*)(ap + k0b * 32);
#pragma unroll
        for (int nb = 0; nb < 8; ++nb) {
            int ncol = nb * 16 + m16;
            bf16x8 bfg = *(const bf16x8*)(wbt + (size_t)ncol * DIM + k0b * 32 + quad * 8);
            acc[nb] = __builtin_amdgcn_mfma_f32_16x16x32_bf16(af, bfg, acc[nb], 0, 0, 0);
        }
    }

    // epilogue: bias, block-shared BN partial stats (LDS atomics), bf16 store
#pragma unroll
    for (int nb = 0; nb < 8; ++nb) {
        int col = nb * 16 + m16;
        float bcol = bias[col];
        float ps = 0.f, pq = 0.f;
#pragma unroll
        for (int reg = 0; reg < 4; ++reg) {
            int r = bnode + quad * 4 + reg;
            if (r < N_NODES) {
                float v = acc[nb][reg] + bcol;
                ps += v; pq += v * v;
                y[(size_t)r * DIM + col] = f2bf(v);
            }
        }
        atomicAdd(&csum[col], ps);
        atomicAdd(&csq[col], pq);
    }
    __syncthreads();  // final barrier: stats complete before global reduce
    if (tid < DIM) {
        atomicAdd(&bnsum[tid], csum[tid]);
        atomicAdd(&bnsq[tid], csq[tid]);
    }
}

// ---------------- pooling: fused layer-3 BN fold+apply + graph counts ----------------
#define POOL_NODES 128
__global__ void k_pool(const ushort_t* __restrict__ yin, const int* __restrict__ gids,
                       const float* __restrict__ bnsum, const float* __restrict__ bnsq,
                       const float* __restrict__ g, const float* __restrict__ be,
                       float* __restrict__ pool, int* __restrict__ cnt) {
    __shared__ int h[N_GRAPHS];
    int col = threadIdx.x;  // 128
    float mu = bnsum[col] * (1.0f / N_NODES);
    float var = bnsq[col] * (1.0f / N_NODES) - mu * mu;
    float rstd = rsqrtf(var + BN_EPS);
    float a = g[col] * rstd;
    float c = be[col] - mu * a;
    if (col < N_GRAPHS) h[col] = 0;
    __syncthreads();
    int base = blockIdx.x * POOL_NODES;
    int end = min(base + POOL_NODES, N_NODES);
    for (int n = base + col; n < end; n += 128) atomicAdd(&h[gids[n]], 1);
    __syncthreads();
    if (col < N_GRAPHS && h[col]) atomicAdd(&cnt[col], h[col]);
    float acc = 0.f;
    int cur = gids[base];
    for (int n = base; n < end; ++n) {
        int gg = gids[n];
        if (gg != cur) {
            atomicAdd(&pool[(size_t)cur * DIM + col], acc);
            acc = 0.f;
            cur = gg;
        }
        uint_t u = *(const uint_t*)(yin + (size_t)n * DIM + (col & ~1));
        float v = (col & 1) ? bfh(u) : bfl(u);
        acc += fmaxf(fmaf(v, a, c), 0.f);
    }
    atomicAdd(&pool[(size_t)cur * DIM + col], acc);
}

// ---------------- final FC (one block per graph) ----------------
__global__ void k_final(const float* __restrict__ pool, const int* __restrict__ cnt,
                        const float* __restrict__ fcW1, const float* __restrict__ fcb1,
                        const float* __restrict__ fcW2, const float* __restrict__ fcb2,
                        float* __restrict__ out) {
    __shared__ float hg[DIM];
    __shared__ float z[64];
    int g = blockIdx.x;
    int t = threadIdx.x;  // 128
    float cf = fmaxf((float)cnt[g], 1.0f);
    hg[t] = pool[(size_t)g * DIM + t] / cf;
    __syncthreads();
    if (t < 64) {
        float acc = fcb1[t];
        for (int k = 0; k < DIM; ++k)
            acc += hg[k] * fcW1[k * 64 + t];
        z[t] = fmaxf(acc, 0.f);
    }
    __syncthreads();
    if (t < 2) {
        float acc = fcb2[t];
        for (int k = 0; k < 64; ++k)
            acc += z[k] * fcW2[k * 2 + t];
        out[g * 2 + t] = acc;
    }
}

extern "C" void kernel_launch(void* const* d_in, const int* in_sizes, int n_in,
                              void* d_out, int out_size, void* d_ws, size_t ws_size,
                              hipStream_t stream) {
    const int* tokens = (const int*)d_in[0];
    const int* src = (const int*)d_in[1];
    const int* dst = (const int*)d_in[2];
    const int* gids = (const int*)d_in[3];
    const float* embed = (const float*)d_in[4];
    const float* W1 = (const float*)d_in[5];
    const float* b1 = (const float*)d_in[6];
    const float* g1 = (const float*)d_in[7];
    const float* be1 = (const float*)d_in[8];
    const float* W2 = (const float*)d_in[9];
    const float* b2 = (const float*)d_in[10];
    const float* g2 = (const float*)d_in[11];
    const float* be2 = (const float*)d_in[12];
    const float* W3 = (const float*)d_in[13];
    const float* b3 = (const float*)d_in[14];
    const float* g3 = (const float*)d_in[15];
    const float* be3 = (const float*)d_in[16];
    const float* fcW1 = (const float*)d_in[17];
    const float* fcb1 = (const float*)d_in[18];
    const float* fcW2 = (const float*)d_in[19];
    const float* fcb2 = (const float*)d_in[20];
    float* out = (float*)d_out;

    char* w = (char*)d_ws;
    auto alloc = [&](size_t bytes) {
        void* p = (void*)w;
        w += (bytes + 255) & ~(size_t)255;
        return p;
    };
    ushort_t* bufH = (ushort_t*)alloc((size_t)(N_NODES + 1) * DIM * 2);  // y2
    ushort_t* bufA = (ushort_t*)alloc((size_t)(N_NODES + 1) * DIM * 2);  // prescaled gather input
    ushort_t* bufY = (ushort_t*)alloc((size_t)(N_NODES + 1) * DIM * 2);  // y1 / y3
    int* esrc = (int*)alloc((size_t)EPAD * 4);
    int* rowptr = (int*)alloc((size_t)N_NODES * 4);
    int* pdeg = (int*)alloc((size_t)N_NODES * 4);
    float* ns = (float*)alloc((size_t)(N_NODES + 1) * 4);
    float* nd = (float*)alloc((size_t)N_NODES * 4);
    ushort_t* wbt = (ushort_t*)alloc(3 * DIM * DIM * 2);
    int* GG = (int*)alloc((size_t)(2 * NG) * 4);
    int* Gs = (int*)alloc((size_t)(2 * NG + 1) * 4);
    int* partials = (int*)alloc(4096 * 4);
    uint_t* Cpk = (uint_t*)alloc((size_t)N_EDGES * 4);
    uchar_t* Cls = (uchar_t*)alloc((size_t)N_EDGES);
    // zeroed region (contiguous)
    char* zstart = w;
    float* bnsum = (float*)alloc(3 * DIM * 4);
    float* bnsq = (float*)alloc(3 * DIM * 4);
    float* pool = (float*)alloc((size_t)N_GRAPHS * DIM * 4);
    int* cnt = (int*)alloc((size_t)N_GRAPHS * 4);
    int zwords = (int)((size_t)(w - zstart) / 4);

    k_front<<<NB_SENT + NB_WPREP + NB_HIST + NB_ZERO, 256, 0, stream>>>(
        src, dst, bufA, esrc, W1, W2, W3, wbt, GG, (int*)zstart, zwords);
    k_scanA<<<NB_SCANG2, 256, 0, stream>>>(GG, Gs, partials);
    k_scanB<<<NB_SCANG2, 256, 0, stream>>>(partials, Gs);
    k_pass2<<<NB_HIST, 256, 0, stream>>>(src, dst, Gs, Cpk, Cls);
    k_fine<<<2 * NBUCK, 256, 0, stream>>>(Cpk, Cls, Gs, tokens, embed,
                                          esrc, rowptr, pdeg, ns, nd, bufA);

    int nb_fused = (N_NODES + 63) / 64;  // 256-thread blocks, 64 nodes each
    int nb_ps = 6250;                    // N*16/256

    // l=0: bufA already holds embed*ns (fused into k_fine); gather -> y1 in bufY
    k_agggemm<<<nb_fused, 256, 0, stream>>>(bufA, rowptr, pdeg, esrc, nd,
                                            wbt, b1, bufY, bnsum, bnsq);
    // l=1: prescale bufY (BN stats1) -> bufA; gather -> y2 in bufH
    k_prescale<<<nb_ps, 256, 0, stream>>>(bufY, ns, bnsum, bnsq, g1, be1, bufA);
    k_agggemm<<<nb_fused, 256, 0, stream>>>(bufA, rowptr, pdeg, esrc, nd,
                                            wbt + (size_t)DIM * DIM, b2, bufH,
                                            bnsum + DIM, bnsq + DIM);
    // l=2: prescale bufH (BN stats2) -> bufA; gather -> y3 in bufY
    k_prescale<<<nb_ps, 256, 0, stream>>>(bufH, ns, bnsum + DIM, bnsq + DIM, g2, be2, bufA);
    k_agggemm<<<nb_fused, 256, 0, stream>>>(bufA, rowptr, pdeg, esrc, nd,
                                            wbt + (size_t)2 * DIM * DIM, b3, bufY,
                                            bnsum + 2 * DIM, bnsq + 2 * DIM);

    k_pool<<<(N_NODES + POOL_NODES - 1) / POOL_NODES, DIM, 0, stream>>>(
        bufY, gids, bnsum + 2 * DIM, bnsq + 2 * DIM, g3, be3, pool, cnt);
    k_final<<<N_GRAPHS, DIM, 0, stream>>>(pool, cnt, fcW1, fcb1, fcW2, fcb2, out);
}